// Round 8
// baseline (143.912 us; speedup 1.0000x reference)
//
#include <hip/hip_runtime.h>

#define SEQ_T 2048
#define HDIM  128
#define NB    16
#define NTILES (SEQ_T / 64)          // 32 kv-tiles of 64
#define TILE_SHORTS 8192             // 16 KB per tile (64x128 bf16)

typedef __attribute__((ext_vector_type(8))) short short8;      // 8 bf16 (4 VGPRs)
typedef __attribute__((ext_vector_type(4))) float float4v;
typedef __attribute__((ext_vector_type(4))) unsigned int uint4v;

#define EXP2F(x) __builtin_amdgcn_exp2f(x)

__device__ __forceinline__ unsigned int bfpack2(float a, float b) {
  unsigned int ua = __builtin_bit_cast(unsigned int, a);
  unsigned int ub = __builtin_bit_cast(unsigned int, b);
  return ((ua + 0x8000u) >> 16) | ((ub + 0x8000u) & 0xFFFF0000u);
}
__device__ __forceinline__ unsigned short f2bf(float a) {
  return (unsigned short)((__builtin_bit_cast(unsigned int, a) + 0x8000u) >> 16);
}
__device__ __forceinline__ float bf2f(unsigned short h) {
  unsigned int u = ((unsigned int)h) << 16;
  return __builtin_bit_cast(float, u);
}

__device__ __forceinline__ float dpp_max16(float x) {
  int t;
  t = __builtin_amdgcn_mov_dpp(__builtin_bit_cast(int, x), 0xB1, 0xF, 0xF, true);
  x = fmaxf(x, __builtin_bit_cast(float, t));
  t = __builtin_amdgcn_mov_dpp(__builtin_bit_cast(int, x), 0x4E, 0xF, 0xF, true);
  x = fmaxf(x, __builtin_bit_cast(float, t));
  t = __builtin_amdgcn_mov_dpp(__builtin_bit_cast(int, x), 0x141, 0xF, 0xF, true);
  x = fmaxf(x, __builtin_bit_cast(float, t));
  t = __builtin_amdgcn_mov_dpp(__builtin_bit_cast(int, x), 0x140, 0xF, 0xF, true);
  x = fmaxf(x, __builtin_bit_cast(float, t));
  return x;
}
__device__ __forceinline__ float dpp_sum16(float x) {
  int t;
  t = __builtin_amdgcn_mov_dpp(__builtin_bit_cast(int, x), 0xB1, 0xF, 0xF, true);
  x += __builtin_bit_cast(float, t);
  t = __builtin_amdgcn_mov_dpp(__builtin_bit_cast(int, x), 0x4E, 0xF, 0xF, true);
  x += __builtin_bit_cast(float, t);
  t = __builtin_amdgcn_mov_dpp(__builtin_bit_cast(int, x), 0x141, 0xF, 0xF, true);
  x += __builtin_bit_cast(float, t);
  t = __builtin_amdgcn_mov_dpp(__builtin_bit_cast(int, x), 0x140, 0xF, 0xF, true);
  x += __builtin_bit_cast(float, t);
  return x;
}

// chunks per batch / partial slots per batch for chunk size CS (super-iters)
// (R5 128-row geometry: super-iters per qb = 2qb+2, qb 0..15)
template<int CS> struct ChunkCfg;
template<> struct ChunkCfg<4> { static const int CPB = 72, SPB = 70, QB0 = 2; };
template<> struct ChunkCfg<8> { static const int CPB = 40, SPB = 36, QB0 = 4; };

// ============================ prepass ============================
// R8 change: V image is stored PER 32-kv HALF (half h contiguous at h*4096
// shorts) with a 4-slot rotation, so the attention kernel can stage 32-kv
// half-tiles for the in-place double buffer. Within half h: slot q (=kbx&3),
// rot ((q+d)&3), holds k-rows {32h+4q+0..3, 32h+16+4q+0..3} (o = ((kbx>>2)&1)*4).
// K tile layout unchanged (row-major, intra-row rotation (u+r)&15 — halves are
// contiguous and the rotation survives half-local rows since 32h = 0 mod 16).
__global__ __launch_bounds__(256) void prepass2(const float* __restrict__ x,
                                                unsigned short* __restrict__ kbuf,
                                                unsigned short* __restrict__ vbuf) {
  const int b = blockIdx.x >> 5;
  const int t = blockIdx.x & 31;
  const int tid = threadIdx.x;
  __shared__ __align__(16) unsigned short Klds[8192];  // [64][128]
  __shared__ __align__(16) unsigned short Vlds[8192];  // [h][d][rot slot][8]

  const float* xb = x + (size_t)b * (SEQ_T * 384) + (size_t)t * 64 * 384;

  for (int i = 0; i < 8; ++i) {
    int idx = tid + i * 256;
    int row = idx >> 5, c4 = (idx & 31) << 2;
    float4v f = *(const float4v*)(xb + (size_t)row * 384 + c4);
    *(uint2*)&Klds[row * 128 + c4] = make_uint2(bfpack2(f[0], f[1]), bfpack2(f[2], f[3]));
  }
  {
    int kb = tid >> 5, db = tid & 31;
    for (int p = 0; p < 2; ++p) {
      int kbx = kb + p * 8;                     // kv block of 4: rows 4kbx..+3
      const float* vb = xb + (size_t)(4 * kbx) * 384 + 256 + 4 * db;
      float4v v0 = *(const float4v*)(vb);
      float4v v1 = *(const float4v*)(vb + 384);
      float4v v2 = *(const float4v*)(vb + 768);
      float4v v3 = *(const float4v*)(vb + 1152);
      int hh = kbx >> 3;                        // half
      int sl = kbx & 3;                         // slot within half
      int o  = ((kbx >> 2) & 1) * 4;
      for (int j = 0; j < 4; ++j) {
        int d = 4 * db + j;
        *(uint2*)&Vlds[hh * 4096 + d * 32 + ((sl + d) & 3) * 8 + o] =
            make_uint2(bfpack2(v0[j], v1[j]), bfpack2(v2[j], v3[j]));
      }
    }
  }
  __syncthreads();

  unsigned short* kdst = kbuf + (size_t)blockIdx.x * TILE_SHORTS;
  unsigned short* vdst = vbuf + (size_t)blockIdx.x * TILE_SHORTS;
  for (int i = 0; i < 4; ++i) {
    int n = tid + i * 256;                       // unit 0..1023
    int r = n >> 4, pu = n & 15, u = (pu - r) & 15;
    *(uint4v*)&kdst[n * 8] = *(const uint4v*)&Klds[r * 128 + u * 8];
    *(uint4v*)&vdst[n * 8] = *(const uint4v*)&Vlds[n * 8];   // already final image
  }
}

// ============================ chunked attention ============================
// R5 PROVEN BASE (42.5us): 128-row blocks, 8 waves, 4 blocks/CU, T14 reg-staged
// prefetch, swapped-QK (P lane-local), permuted V image (PV = one rot-swizzled
// ds_read_b128). R8 (this round): KVBLK=32 IN-PLACE double buffer — two
// {K 8KB + V 8KB} buffers fit the SAME 32 KB (4 blocks/CU preserved), one
// barrier per 32-kv tile (same barrier count per kv as R5), ds_writes and the
// t+2 reg prefetch overlap the other buffer's compute. Protocol = R6's verified
// single-barrier invariant (R6 failed on occupancy, not correctness).
// LEDGER:
//  * single-barrier global_load_lds DMA: corrupted TWICE (prior R9; R1) — banned.
//  * R4 V b64 pair-read: 4-way bank conflict — retired.
//  * R6 256-row/2-blocks-per-CU: +24% — inter-block TLP (4 blocks/CU) is the
//    dominant latency-hiding resource; never trade it away.
//  * R7 T5 setprio around MFMA clusters: −12% (priority-starves the staging
//    waves when every wave wraps 90% of its body) — retired.
// launch_bounds(512,4): (512,8) collapses the allocator (prior session R7).
template<int CS>
__global__ __launch_bounds__(512, 4) void attn_chunk_k(const float* __restrict__ x,
                                                       const unsigned short* __restrict__ kbuf,
                                                       const unsigned short* __restrict__ vbuf,
                                                       unsigned short* __restrict__ Opart,
                                                       float* __restrict__ mlpart,
                                                       float* __restrict__ out) {
  const int f = blockIdx.x;
  const int b = f / ChunkCfg<CS>::CPB;
  const int c = f - b * ChunkCfg<CS>::CPB;
  int qb = 0, cum = 0;
  for (;;) {
    int gg = (2 * qb + 2 + CS - 1) / CS;
    if (c < cum + gg) break;
    cum += gg; ++qb;
  }
  const int g = (2 * qb + 2 + CS - 1) / CS;
  const int k = c - cum;
  const int sBeg = k * CS;
  const int sEnd = min(sBeg + CS, 2 * qb + 2);

  const int tid  = threadIdx.x;
  const int qt   = tid >> 6;
  const int lane = tid & 63;
  const int low  = lane & 15;
  const int quad = lane >> 4;
  const int q0   = qb * 128 + qt * 16;

  // two half-tile buffers in 32 KB: buf0 {K@0, V@8192}, buf1 {K@16384, V@24576}
  __shared__ __align__(16) unsigned short smem[16384];

  const float* xb = x + (size_t)b * (SEQ_T * 3 * HDIM);
  const unsigned short* kt = kbuf + (size_t)b * NTILES * TILE_SHORTS;
  const unsigned short* vt = vbuf + (size_t)b * NTILES * TILE_SHORTS;

  const float qs = 0.08838834764831845f * 1.4426950408889634f;
  short8 qa[4];
  {
    const float* qrow = xb + (size_t)(q0 + low) * 384 + 128;
    for (int kc = 0; kc < 4; ++kc) {
      float4v f0 = *(const float4v*)(qrow + kc * 32 + quad * 8);
      float4v f1 = *(const float4v*)(qrow + kc * 32 + quad * 8 + 4);
      uint4v u = { bfpack2(f0[0] * qs, f0[1] * qs), bfpack2(f0[2] * qs, f0[3] * qs),
                   bfpack2(f1[0] * qs, f1[1] * qs), bfpack2(f1[2] * qs, f1[3] * qs) };
      qa[kc] = __builtin_bit_cast(short8, u);
    }
  }

  float4v accv[8];
  for (int i = 0; i < 8; ++i) accv[i] = (float4v){0.f, 0.f, 0.f, 0.f};
  float l = 0.f;                         // per-lane: q-row = low

  const int so = qt * 512 + lane * 8;    // this wave's staging slice within a half

  const int tBeg = 2 * sBeg, tEnd = 2 * sEnd;   // 32-kv tile index
  // global offset of half-tile t, this wave's slice:
  //   kt/vt + (t>>1)*TILE_SHORTS + (t&1)*4096 + so
#define HTOFF(t) ((size_t)((t) >> 1) * TILE_SHORTS + (size_t)(((t) & 1)) * 4096 + so)

  // prologue: stage tile tBeg into buf0 (visible after first barrier)
  uint4v kr, vr;
  {
    uint4v k0 = *(const uint4v*)(kt + HTOFF(tBeg));
    uint4v v0 = *(const uint4v*)(vt + HTOFF(tBeg));
    *(uint4v*)&smem[so]        = k0;
    *(uint4v*)&smem[4096 + so] = v0;
  }
  if (tBeg + 1 < tEnd) {   // preload t+1 into regs
    kr = *(const uint4v*)(kt + HTOFF(tBeg + 1));
    vr = *(const uint4v*)(vt + HTOFF(tBeg + 1));
  }

  int cur = 0;
  for (int t = tBeg; t < tEnd; ++t) {
    __syncthreads();   // buf[cur] (tile t) visible; all waves done reading buf[cur^1]

    if (t + 1 < tEnd) {                  // publish t+1 into the free buffer
      unsigned short* Kb = smem + (cur ^ 1) * 8192;
      *(uint4v*)&Kb[so]        = kr;
      *(uint4v*)&Kb[4096 + so] = vr;
    }
    if (t + 2 < tEnd) {                  // prefetch t+2; hides under compute below
      kr = *(const uint4v*)(kt + HTOFF(t + 2));
      vr = *(const uint4v*)(vt + HTOFF(t + 2));
    }

    const int c0 = t * 32;
    if (c0 <= q0 + 15) {
      const unsigned short* Ks = smem + cur * 8192;         // 32 rows x 128 d
      const unsigned short* Vh = Ks + 4096;                  // half V image
      const int Ra = low;
      const int Rb = low + 16;
      float4v s0 = {0.f,0.f,0.f,0.f}, s1 = {0.f,0.f,0.f,0.f};
      for (int kc = 0; kc < 4; ++kc) {
        short8 kf0 = *(const short8*)&Ks[Ra * 128 + (((kc * 4 + quad) + Ra) & 15) * 8];
        short8 kf1 = *(const short8*)&Ks[Rb * 128 + (((kc * 4 + quad) + Rb) & 15) * 8];
        // SWAPPED: S^T = K . Q^T -> lane(low,quad) reg r = P[q0+low][c0 + quad*4 + r]
        s0 = __builtin_amdgcn_mfma_f32_16x16x32_bf16(kf0, qa[kc], s0, 0, 0, 0);
        s1 = __builtin_amdgcn_mfma_f32_16x16x32_bf16(kf1, qa[kc], s1, 0, 0, 0);
      }
      if (c0 + 31 > q0) {
        const int qrow = q0 + low;
        for (int r = 0; r < 4; ++r) {
          s0[r] = (c0 + quad * 4 + r      <= qrow) ? s0[r] : -1e30f;
          s1[r] = (c0 + 16 + quad * 4 + r <= qrow) ? s1[r] : -1e30f;
        }
      }
      // max-free softmax: P = exp2(s); l accumulates lane-locally (q-row = low)
      for (int r = 0; r < 4; ++r) {
        s0[r] = EXP2F(s0[r]);               // masked -1e30 -> 0
        s1[r] = EXP2F(s1[r]);
      }
      l += (s0[0] + s0[1]) + (s0[2] + s0[3]) + (s1[0] + s1[1]) + (s1[2] + s1[3]);

      // P A-fragment, k-permuted: pi(p=8q+j) = 4q+(j&3)+16*(j>=4) — in registers
      uint4v pu = { bfpack2(s0[0], s0[1]), bfpack2(s0[2], s0[3]),
                    bfpack2(s1[0], s1[1]), bfpack2(s1[2], s1[3]) };
      short8 pa = __builtin_bit_cast(short8, pu);

      // V B-fragment: slot quad of the per-half rot image = one b128 read
      for (int nt = 0; nt < 8; ++nt) {
        int d = nt * 16 + low;
        short8 vf = *(const short8*)&Vh[d * 32 + ((quad + d) & 3) * 8];
        accv[nt] = __builtin_amdgcn_mfma_f32_16x16x32_bf16(pa, vf, accv[nt], 0, 0, 0);
      }
    }
    cur ^= 1;
  }
#undef HTOFF

  // reduce l across quads (lanes low, low+16, low+32, low+48 share q-row = low)
  l += __shfl_xor(l, 16);
  l += __shfl_xor(l, 32);
  // redistribute to accv row layout: row = quad*4 + r
  float lr[4];
  for (int r = 0; r < 4; ++r) lr[r] = __shfl(l, quad * 4 + r);

  if (g == 1) {
    float inv[4];
    for (int r = 0; r < 4; ++r) inv[r] = 1.f / lr[r];
    float* ob = out + ((size_t)b * SEQ_T + q0) * HDIM;
    for (int nt = 0; nt < 8; ++nt)
      for (int r = 0; r < 4; ++r)
        ob[(size_t)(quad * 4 + r) * HDIM + nt * 16 + low] = accv[nt][r] * inv[r];
  } else {
    const int slot = b * ChunkCfg<CS>::SPB + (cum - ChunkCfg<CS>::QB0) + k;
    unsigned short* op = Opart + (size_t)slot * 16384 + (size_t)qt * 16 * 128;
    for (int nt = 0; nt < 8; ++nt)
      for (int r = 0; r < 4; ++r)
        op[(size_t)(quad * 4 + r) * 128 + nt * 16 + low] = f2bf(accv[nt][r]);
    if (low == 0) {
      float* ml = mlpart + (size_t)slot * 256;
      for (int r = 0; r < 4; ++r)
        ml[qt * 16 + quad * 4 + r] = lr[r];   // shared scale: only l needed
    }
  }
}

// ============================ merge (no max, no exp2) ============================
template<int CS>
__global__ __launch_bounds__(256) void merge_k(const unsigned short* __restrict__ Opart,
                                               const float* __restrict__ mlpart,
                                               float* __restrict__ out) {
  const int QB0 = ChunkCfg<CS>::QB0;
  const int rowsPB = (16 - QB0) * 128;
  const int ri  = blockIdx.x * 2 + (threadIdx.x >> 7);
  const int b   = ri / rowsPB;
  const int r2  = ri - b * rowsPB;
  const int qb  = QB0 + (r2 >> 7);
  const int row = r2 & 127;
  const int d   = threadIdx.x & 127;
  const int g   = (2 * qb + 2 + CS - 1) / CS;
  int cum = 0;
  for (int i = 0; i < qb; ++i) cum += (2 * i + 2 + CS - 1) / CS;
  const int s0 = b * ChunkCfg<CS>::SPB + cum - QB0;

  float num = 0.f, den = 0.f;
  for (int k = 0; k < g; ++k) {
    den += mlpart[(size_t)(s0 + k) * 256 + row];
    num += bf2f(Opart[(size_t)(s0 + k) * 16384 + (size_t)row * 128 + d]);
  }
  out[((size_t)b * SEQ_T + qb * 128 + row) * HDIM + d] = num / den;
}

// ============================ no-ws fallback (R4, online softmax) ============================
__global__ __launch_bounds__(512, 4) void attn_fb(const float* __restrict__ x,
                                                  float* __restrict__ out) {
  const int b    = blockIdx.y;
  const int qblk = (int)gridDim.x - 1 - (int)blockIdx.x;
  const int qb0  = qblk << 6;
  const int tid  = threadIdx.x;
  const int wave = tid >> 6;
  const int lane = tid & 63;
  const int low  = lane & 15;
  const int quad = lane >> 4;
  const int qt   = wave & 3;
  const int half = wave >> 2;
  const int q0   = qb0 + (qt << 4);
  __shared__ __align__(16) unsigned char smem[48128];
  unsigned short* Ks = (unsigned short*)smem;
  unsigned short* Vt = (unsigned short*)(smem + 17408);
  unsigned short* Ps = (unsigned short*)(smem + 37888);
  float* Om = (float*)smem;
  float* Ml = (float*)(smem + 33792);
  const float* xb = x + (size_t)b * (SEQ_T * 3 * HDIM);
  const float qs = 0.08838834764831845f * 1.4426950408889634f;
  short8 qa[4];
  {
    const float* qrow = xb + (size_t)(q0 + low) * 384 + 128;
    for (int kc = 0; kc < 4; ++kc) {
      float4v f0 = *(const float4v*)(qrow + kc * 32 + quad * 8);
      float4v f1 = *(const float4v*)(qrow + kc * 32 + quad * 8 + 4);
      uint4v u = { bfpack2(f0[0] * qs, f0[1] * qs), bfpack2(f0[2] * qs, f0[3] * qs),
                   bfpack2(f1[0] * qs, f1[1] * qs), bfpack2(f1[2] * qs, f1[3] * qs) };
      qa[kc] = __builtin_bit_cast(short8, u);
    }
  }
  float4v accv[8];
  for (int i = 0; i < 8; ++i) accv[i] = (float4v){0.f, 0.f, 0.f, 0.f};
  float m_i[4] = {-1e30f, -1e30f, -1e30f, -1e30f};
  float l_i[4] = {0.f, 0.f, 0.f, 0.f};
  const int nsuper = qblk + 1;
  for (int s = 0; s < nsuper; ++s) {
    const int r0 = s << 6;
    __syncthreads();
    for (int i = 0; i < 4; ++i) {
      int f = tid + (i << 9);
      int row = f >> 5;
      int c4 = (f & 31) << 2;
      float4v kf = *(const float4v*)(xb + (size_t)(r0 + row) * 384 + c4);
      *(uint2*)&Ks[(row >> 5) * 4352 + (row & 31) * 136 + c4] =
          make_uint2(bfpack2(kf[0], kf[1]), bfpack2(kf[2], kf[3]));
    }
    {
      int kb = tid >> 5, db = tid & 31;
      int til = kb >> 3, kbl = kb & 7;
      const float* vbase = xb + (size_t)(r0 + 4 * kb) * 384 + 256 + 4 * db;
      float4v v0 = *(const float4v*)(vbase);
      float4v v1 = *(const float4v*)(vbase + 384);
      float4v v2 = *(const float4v*)(vbase + 768);
      float4v v3 = *(const float4v*)(vbase + 1152);
      unsigned short* vv = Vt + til * 5120;
      for (int j = 0; j < 4; ++j) {
        int d = 4 * db + j;
        int pb = ((kbl >> 1) + (d >> 3)) & 3;
        *(uint2*)&vv[d * 40 + pb * 8 + (kbl & 1) * 4] =
            make_uint2(bfpack2(v0[j], v1[j]), bfpack2(v2[j], v3[j]));
      }
    }
    __syncthreads();
    const int c0 = r0 + (half << 5);
    if (c0 <= q0 + 15) {
      const unsigned short* Ksp = Ks + half * 4352;
      const unsigned short* Vtp = Vt + half * 5120;
      float4v s0 = {0.f,0.f,0.f,0.f}, s1 = {0.f,0.f,0.f,0.f};
      for (int kc = 0; kc < 4; ++kc) {
        short8 kf0 = *(const short8*)&Ksp[low * 136 + kc * 32 + quad * 8];
        short8 kf1 = *(const short8*)&Ksp[(16 + low) * 136 + kc * 32 + quad * 8];
        s0 = __builtin_amdgcn_mfma_f32_16x16x32_bf16(qa[kc], kf0, s0, 0, 0, 0);
        s1 = __builtin_amdgcn_mfma_f32_16x16x32_bf16(qa[kc], kf1, s1, 0, 0, 0);
      }
      if (c0 + 31 > q0) {
        for (int r = 0; r < 4; ++r) {
          int qrow = q0 + quad * 4 + r;
          s0[r] = (c0 + low      <= qrow) ? s0[r] : -1e30f;
          s1[r] = (c0 + 16 + low <= qrow) ? s1[r] : -1e30f;
        }
      }
      float rmax[4], alpha[4];
      for (int r = 0; r < 4; ++r) rmax[r] = dpp_max16(fmaxf(s0[r], s1[r]));
      for (int r = 0; r < 4; ++r) {
        float mn = fmaxf(m_i[r], rmax[r]);
        alpha[r] = EXP2F(m_i[r] - mn);
        m_i[r] = mn;
      }
      for (int r = 0; r < 4; ++r) {
        s0[r] = EXP2F(s0[r] - m_i[r]);
        s1[r] = EXP2F(s1[r] - m_i[r]);
      }
      float rs[4];
      for (int r = 0; r < 4; ++r) rs[r] = dpp_sum16(s0[r] + s1[r]);
      for (int r = 0; r < 4; ++r) l_i[r] = l_i[r] * alpha[r] + rs[r];
      for (int nt = 0; nt < 8; ++nt)
        for (int r = 0; r < 4; ++r) accv[nt][r] *= alpha[r];
      unsigned short* pw = Ps + wave * 640;
      for (int r = 0; r < 4; ++r) {
        int row = quad * 4 + r;
        pw[row * 40 + low]      = f2bf(s0[r]);
        pw[row * 40 + 16 + low] = f2bf(s1[r]);
      }
      short8 pa = *(const short8*)&pw[low * 40 + quad * 8];
      for (int nt = 0; nt < 8; ++nt) {
        int d = nt * 16 + low;
        int pb = (quad + (d >> 3)) & 3;
        short8 vf = *(const short8*)&Vtp[d * 40 + pb * 8];
        accv[nt] = __builtin_amdgcn_mfma_f32_16x16x32_bf16(pa, vf, accv[nt], 0, 0, 0);
      }
    }
  }
  __syncthreads();
  if (half == 1) {
    float* om = Om + qt * 2112;
    for (int nt = 0; nt < 8; ++nt)
      for (int r = 0; r < 4; ++r)
        om[(quad * 4 + r) * 132 + nt * 16 + low] = accv[nt][r];
    if (low == 0) {
      for (int r = 0; r < 4; ++r) {
        Ml[qt * 32 + quad * 4 + r]      = m_i[r];
        Ml[qt * 32 + 16 + quad * 4 + r] = l_i[r];
      }
    }
  }
  __syncthreads();
  if (half == 0) {
    float aA[4], aB[4], linv[4];
    for (int r = 0; r < 4; ++r) {
      float mB = Ml[qt * 32 + quad * 4 + r];
      float lB = Ml[qt * 32 + 16 + quad * 4 + r];
      float mN = fmaxf(m_i[r], mB);
      aA[r] = EXP2F(m_i[r] - mN);
      aB[r] = EXP2F(mB - mN);
      linv[r] = 1.f / (l_i[r] * aA[r] + lB * aB[r]);
    }
    const float* om = Om + qt * 2112;
    float* ob = out + ((size_t)b * SEQ_T + q0) * HDIM;
    for (int nt = 0; nt < 8; ++nt)
      for (int r = 0; r < 4; ++r) {
        float o = accv[nt][r] * aA[r] + om[(quad * 4 + r) * 132 + nt * 16 + low] * aB[r];
        ob[(size_t)(quad * 4 + r) * HDIM + nt * 16 + low] = o * linv[r];
      }
  }
}

extern "C" void kernel_launch(void* const* d_in, const int* in_sizes, int n_in,
                              void* d_out, int out_size, void* d_ws, size_t ws_size,
                              hipStream_t stream) {
  const float* x = (const float*)d_in[0];
  float* out = (float*)d_out;
  const size_t PRE = (size_t)NB * NTILES * TILE_SHORTS * 2 * sizeof(unsigned short); // 16 MB

  const size_t OP4 = (size_t)NB * 70 * 16384 * sizeof(unsigned short);   // 36.7 MB
  const size_t ML4 = (size_t)NB * 70 * 256 * sizeof(float);
  const size_t OP8 = (size_t)NB * 36 * 16384 * sizeof(unsigned short);   // 18.9 MB
  const size_t ML8 = (size_t)NB * 36 * 256 * sizeof(float);

  unsigned short* kbuf = (unsigned short*)d_ws;
  unsigned short* vbuf = kbuf + (size_t)NB * NTILES * TILE_SHORTS;

  if (ws_size >= PRE + OP4 + ML4) {
    unsigned short* Opart = (unsigned short*)((char*)d_ws + PRE);
    float*          mlp   = (float*)((char*)d_ws + PRE + OP4);
    hipLaunchKernelGGL(prepass2, dim3(NB * NTILES), dim3(256), 0, stream, x, kbuf, vbuf);
    hipLaunchKernelGGL((attn_chunk_k<4>), dim3(NB * 72), dim3(512), 0, stream,
                       x, kbuf, vbuf, Opart, mlp, out);
    hipLaunchKernelGGL((merge_k<4>), dim3(NB * 14 * 128 / 2), dim3(256), 0, stream,
                       Opart, mlp, out);
  } else if (ws_size >= PRE + OP8 + ML8) {
    unsigned short* Opart = (unsigned short*)((char*)d_ws + PRE);
    float*          mlp   = (float*)((char*)d_ws + PRE + OP8);
    hipLaunchKernelGGL(prepass2, dim3(NB * NTILES), dim3(256), 0, stream, x, kbuf, vbuf);
    hipLaunchKernelGGL((attn_chunk_k<8>), dim3(NB * 40), dim3(512), 0, stream,
                       x, kbuf, vbuf, Opart, mlp, out);
    hipLaunchKernelGGL((merge_k<8>), dim3(NB * 12 * 128 / 2), dim3(256), 0, stream,
                       Opart, mlp, out);
  } else {
    hipLaunchKernelGGL(attn_fb, dim3(SEQ_T / 64, NB), dim3(512), 0, stream, x, out);
  }
}

// Round 9
// 142.149 us; speedup vs baseline: 1.0124x; 1.0124x over previous
//
#include <hip/hip_runtime.h>

#define SEQ_T 2048
#define HDIM  128
#define NB    16
#define NTILES (SEQ_T / 64)          // 32 kv-tiles of 64
#define TILE_SHORTS 8192             // 16 KB per tile (64x128 bf16)

typedef __attribute__((ext_vector_type(8))) short short8;      // 8 bf16 (4 VGPRs)
typedef __attribute__((ext_vector_type(4))) float float4v;
typedef __attribute__((ext_vector_type(4))) unsigned int uint4v;

#define EXP2F(x) __builtin_amdgcn_exp2f(x)

__device__ __forceinline__ unsigned int bfpack2(float a, float b) {
  unsigned int ua = __builtin_bit_cast(unsigned int, a);
  unsigned int ub = __builtin_bit_cast(unsigned int, b);
  return ((ua + 0x8000u) >> 16) | ((ub + 0x8000u) & 0xFFFF0000u);
}
__device__ __forceinline__ unsigned short f2bf(float a) {
  return (unsigned short)((__builtin_bit_cast(unsigned int, a) + 0x8000u) >> 16);
}
__device__ __forceinline__ float bf2f(unsigned short h) {
  unsigned int u = ((unsigned int)h) << 16;
  return __builtin_bit_cast(float, u);
}

__device__ __forceinline__ float dpp_max16(float x) {
  int t;
  t = __builtin_amdgcn_mov_dpp(__builtin_bit_cast(int, x), 0xB1, 0xF, 0xF, true);
  x = fmaxf(x, __builtin_bit_cast(float, t));
  t = __builtin_amdgcn_mov_dpp(__builtin_bit_cast(int, x), 0x4E, 0xF, 0xF, true);
  x = fmaxf(x, __builtin_bit_cast(float, t));
  t = __builtin_amdgcn_mov_dpp(__builtin_bit_cast(int, x), 0x141, 0xF, 0xF, true);
  x = fmaxf(x, __builtin_bit_cast(float, t));
  t = __builtin_amdgcn_mov_dpp(__builtin_bit_cast(int, x), 0x140, 0xF, 0xF, true);
  x = fmaxf(x, __builtin_bit_cast(float, t));
  return x;
}
__device__ __forceinline__ float dpp_sum16(float x) {
  int t;
  t = __builtin_amdgcn_mov_dpp(__builtin_bit_cast(int, x), 0xB1, 0xF, 0xF, true);
  x += __builtin_bit_cast(float, t);
  t = __builtin_amdgcn_mov_dpp(__builtin_bit_cast(int, x), 0x4E, 0xF, 0xF, true);
  x += __builtin_bit_cast(float, t);
  t = __builtin_amdgcn_mov_dpp(__builtin_bit_cast(int, x), 0x141, 0xF, 0xF, true);
  x += __builtin_bit_cast(float, t);
  t = __builtin_amdgcn_mov_dpp(__builtin_bit_cast(int, x), 0x140, 0xF, 0xF, true);
  x += __builtin_bit_cast(float, t);
  return x;
}

// chunks per batch / partial slots per batch for chunk size CS (super-iters)
// (R5 128-row geometry: super-iters per qb = 2qb+2, qb 0..15)
template<int CS> struct ChunkCfg;
template<> struct ChunkCfg<4> { static const int CPB = 72, SPB = 70, QB0 = 2; };
template<> struct ChunkCfg<8> { static const int CPB = 40, SPB = 36, QB0 = 4; };

// ============================ prepass (R9: half-tile split, 2x parallelism) ============================
// Produces BIT-IDENTICAL kbuf/vbuf images to the R5 prepass (V image: slot
// sl=4h'+q rot-swizzled by +d over 8 slots x 8 shorts per d). One block per
// (b, 64-kv tile, half): K half = rows [32h,32h+32) (rotation is mod-16 so it
// survives row-splitting); V half = d-columns [64h,64h+64) (each V column needs
// all 64 rows, which this block reads). 1024 blocks x 256 thr, 16 KB LDS ->
// ~16 waves/CU vs the old 8 (old prepass: 512 blocks, latency-bound).
__global__ __launch_bounds__(256) void prepass2(const float* __restrict__ x,
                                                unsigned short* __restrict__ kbuf,
                                                unsigned short* __restrict__ vbuf) {
  const int bid = blockIdx.x;
  const int b   = bid >> 6;            // 64 half-tiles per batch
  const int rem = bid & 63;
  const int t   = rem >> 1;            // 64-kv tile
  const int h   = rem & 1;             // half
  const int tid = threadIdx.x;
  __shared__ __align__(16) unsigned short Klds[4096];  // [32 rows][128 cols]
  __shared__ __align__(16) unsigned short Vlds[4096];  // local d in [0,64): [d][slot][8]

  const float* xb = x + (size_t)b * (SEQ_T * 384) + (size_t)t * 64 * 384;

  // K: rows 32h..32h+31, cols 0..127
  for (int i = 0; i < 4; ++i) {
    int idx = tid + i * 256;                    // 0..1023
    int rl = idx >> 5, c4 = (idx & 31) << 2;
    float4v f = *(const float4v*)(xb + (size_t)(32 * h + rl) * 384 + c4);
    *(uint2*)&Klds[rl * 128 + c4] = make_uint2(bfpack2(f[0], f[1]), bfpack2(f[2], f[3]));
  }
  // V: all 64 rows, cols 64h..64h+63
  {
    int kb = tid >> 4, db2 = tid & 15;          // kb: 16 groups of 4 rows
    int c4 = 64 * h + 4 * db2;
    const float* vb = xb + (size_t)(4 * kb) * 384 + 256 + c4;
    float4v v0 = *(const float4v*)(vb);
    float4v v1 = *(const float4v*)(vb + 384);
    float4v v2 = *(const float4v*)(vb + 768);
    float4v v3 = *(const float4v*)(vb + 1152);
    int sl = ((kb >> 3) << 2) | (kb & 3);       // permuted slot (R5 mapping)
    int o  = ((kb >> 2) & 1) * 4;
    for (int j = 0; j < 4; ++j) {
      int d = c4 + j;
      *(uint2*)&Vlds[(d - 64 * h) * 64 + ((sl + d) & 7) * 8 + o] =
          make_uint2(bfpack2(v0[j], v1[j]), bfpack2(v2[j], v3[j]));
    }
  }
  __syncthreads();

  unsigned short* kdst = kbuf + (size_t)(b * NTILES + t) * TILE_SHORTS;
  unsigned short* vdst = vbuf + (size_t)(b * NTILES + t) * TILE_SHORTS;
  for (int i = 0; i < 2; ++i) {
    int nloc = tid + i * 256;                   // 0..511
    int n = 512 * h + nloc;                     // global unit
    int rl = nloc >> 4, pu = nloc & 15;
    int u = (pu - (32 * h + rl)) & 15;          // == (pu - rl) & 15 since 32h%16==0
    *(uint4v*)&kdst[n * 8] = *(const uint4v*)&Klds[rl * 128 + u * 8];
    *(uint4v*)&vdst[n * 8] = *(const uint4v*)&Vlds[nloc * 8];  // final image
  }
}

// ============================ chunked attention (R5 PROVEN, verbatim) ============================
// 42.5us: 128-row blocks, 8 waves, 4 blocks/CU, two-barrier T14 reg-staged
// prefetch, swapped-QK (P lane-local), permuted V image (PV = one rot-swizzled
// ds_read_b128).
// LEDGER:
//  * single-barrier global_load_lds DMA: corrupted TWICE — banned.
//  * R4 V b64 pair-read: 4-way bank conflict — retired.
//  * R6 256-row/2-blocks-per-CU: +24% — inter-block TLP (4 blocks/CU) is the
//    dominant latency-hiding resource; never trade it away.
//  * R7 T5 setprio around MFMA clusters: −12% (starves staging waves) — retired.
//  * R8 KVBLK=32 V half-image: conflicts 2.13M->4.26M, +6us — the 8-slot/64-short
//    rotation is load-bearing; retired.
// launch_bounds(512,4): (512,8) collapses the allocator (prior session R7).
template<int CS>
__global__ __launch_bounds__(512, 4) void attn_chunk_k(const float* __restrict__ x,
                                                       const unsigned short* __restrict__ kbuf,
                                                       const unsigned short* __restrict__ vbuf,
                                                       unsigned short* __restrict__ Opart,
                                                       float* __restrict__ mlpart,
                                                       float* __restrict__ out) {
  const int f = blockIdx.x;
  const int b = f / ChunkCfg<CS>::CPB;
  const int c = f - b * ChunkCfg<CS>::CPB;
  int qb = 0, cum = 0;
  for (;;) {
    int gg = (2 * qb + 2 + CS - 1) / CS;
    if (c < cum + gg) break;
    cum += gg; ++qb;
  }
  const int g = (2 * qb + 2 + CS - 1) / CS;
  const int k = c - cum;
  const int sBeg = k * CS;
  const int sEnd = min(sBeg + CS, 2 * qb + 2);

  const int tid  = threadIdx.x;
  const int qt   = tid >> 6;
  const int lane = tid & 63;
  const int low  = lane & 15;
  const int quad = lane >> 4;
  const int q0   = qb * 128 + qt * 16;

  __shared__ __align__(16) unsigned char smem[32768];    // K tile + V tile only
  unsigned short* Ks = (unsigned short*)smem;            // 16 KB swizzled K tile
  unsigned short* Vt = (unsigned short*)(smem + 16384);  // 16 KB swizzled V^T tile

  const float* xb = x + (size_t)b * (SEQ_T * 3 * HDIM);
  const unsigned short* kt = kbuf + (size_t)b * NTILES * TILE_SHORTS;
  const unsigned short* vt = vbuf + (size_t)b * NTILES * TILE_SHORTS;

  const float qs = 0.08838834764831845f * 1.4426950408889634f;
  short8 qa[4];
  {
    const float* qrow = xb + (size_t)(q0 + low) * 384 + 128;
    for (int kc = 0; kc < 4; ++kc) {
      float4v f0 = *(const float4v*)(qrow + kc * 32 + quad * 8);
      float4v f1 = *(const float4v*)(qrow + kc * 32 + quad * 8 + 4);
      uint4v u = { bfpack2(f0[0] * qs, f0[1] * qs), bfpack2(f0[2] * qs, f0[3] * qs),
                   bfpack2(f1[0] * qs, f1[1] * qs), bfpack2(f1[2] * qs, f1[3] * qs) };
      qa[kc] = __builtin_bit_cast(short8, u);
    }
  }

  float4v accv[8];
  for (int i = 0; i < 8; ++i) accv[i] = (float4v){0.f, 0.f, 0.f, 0.f};
  float l = 0.f;                         // per-lane: q-row = low

  const int ch = qt * 2;

  // T14 staging registers: this wave's 2 K-chunks + 2 V-chunks, 16B/lane each
  uint4v kr0, kr1, vr0, vr1;
  {
    const unsigned short* ksrc = kt + (size_t)sBeg * TILE_SHORTS;
    const unsigned short* vsrc = vt + (size_t)sBeg * TILE_SHORTS;
    kr0 = *(const uint4v*)(ksrc + (size_t)ch * 512 + lane * 8);
    kr1 = *(const uint4v*)(ksrc + (size_t)(ch + 1) * 512 + lane * 8);
    vr0 = *(const uint4v*)(vsrc + (size_t)ch * 512 + lane * 8);
    vr1 = *(const uint4v*)(vsrc + (size_t)(ch + 1) * 512 + lane * 8);
  }

  for (int s = sBeg; s < sEnd; ++s) {
    __syncthreads();   // all waves done reading previous tile; prev prefetch drained

    *(uint4v*)&Ks[(size_t)ch * 512 + lane * 8]       = kr0;
    *(uint4v*)&Ks[(size_t)(ch + 1) * 512 + lane * 8] = kr1;
    *(uint4v*)&Vt[(size_t)ch * 512 + lane * 8]       = vr0;
    *(uint4v*)&Vt[(size_t)(ch + 1) * 512 + lane * 8] = vr1;

    __syncthreads();   // tile-s image visible to all waves

    if (s + 1 < sEnd) {   // prefetch next tile; latency hides under compute below
      const unsigned short* ksrc = kt + (size_t)(s + 1) * TILE_SHORTS;
      const unsigned short* vsrc = vt + (size_t)(s + 1) * TILE_SHORTS;
      kr0 = *(const uint4v*)(ksrc + (size_t)ch * 512 + lane * 8);
      kr1 = *(const uint4v*)(ksrc + (size_t)(ch + 1) * 512 + lane * 8);
      vr0 = *(const uint4v*)(vsrc + (size_t)ch * 512 + lane * 8);
      vr1 = *(const uint4v*)(vsrc + (size_t)(ch + 1) * 512 + lane * 8);
    }

    for (int h = 0; h < 2; ++h) {
      const int c0 = s * 64 + h * 32;
      if (c0 > q0 + 15) continue;
      const int Ra = (h << 5) + low;
      const int Rb = Ra + 16;
      float4v s0 = {0.f,0.f,0.f,0.f}, s1 = {0.f,0.f,0.f,0.f};
      for (int kc = 0; kc < 4; ++kc) {
        short8 kf0 = *(const short8*)&Ks[Ra * 128 + (((kc * 4 + quad) + Ra) & 15) * 8];
        short8 kf1 = *(const short8*)&Ks[Rb * 128 + (((kc * 4 + quad) + Rb) & 15) * 8];
        // SWAPPED: S^T = K . Q^T -> lane(low,quad) reg r = P[q0+low][c0 + quad*4 + r]
        s0 = __builtin_amdgcn_mfma_f32_16x16x32_bf16(kf0, qa[kc], s0, 0, 0, 0);
        s1 = __builtin_amdgcn_mfma_f32_16x16x32_bf16(kf1, qa[kc], s1, 0, 0, 0);
      }
      if (c0 + 31 > q0) {
        const int qrow = q0 + low;
        for (int r = 0; r < 4; ++r) {
          s0[r] = (c0 + quad * 4 + r      <= qrow) ? s0[r] : -1e30f;
          s1[r] = (c0 + 16 + quad * 4 + r <= qrow) ? s1[r] : -1e30f;
        }
      }
      // max-free softmax: P = exp2(s); l accumulates lane-locally (q-row = low)
      for (int r = 0; r < 4; ++r) {
        s0[r] = EXP2F(s0[r]);               // masked -1e30 -> 0
        s1[r] = EXP2F(s1[r]);
      }
      l += (s0[0] + s0[1]) + (s0[2] + s0[3]) + (s1[0] + s1[1]) + (s1[2] + s1[3]);

      // P A-fragment, k-permuted: pi(p=8q+j) = 4q+(j&3)+16*(j>=4) — in registers
      uint4v pu = { bfpack2(s0[0], s0[1]), bfpack2(s0[2], s0[3]),
                    bfpack2(s1[0], s1[1]), bfpack2(s1[2], s1[3]) };
      short8 pa = __builtin_bit_cast(short8, pu);

      // V B-fragment: slot sl=4h+quad of the permuted image = one b128 read
      const int sl = (h << 2) + quad;
      for (int nt = 0; nt < 8; ++nt) {
        int d = nt * 16 + low;
        short8 vf = *(const short8*)&Vt[d * 64 + ((sl + d) & 7) * 8];
        accv[nt] = __builtin_amdgcn_mfma_f32_16x16x32_bf16(pa, vf, accv[nt], 0, 0, 0);
      }
    }
  }

  // reduce l across quads (lanes low, low+16, low+32, low+48 share q-row = low)
  l += __shfl_xor(l, 16);
  l += __shfl_xor(l, 32);
  // redistribute to accv row layout: row = quad*4 + r
  float lr[4];
  for (int r = 0; r < 4; ++r) lr[r] = __shfl(l, quad * 4 + r);

  if (g == 1) {
    float inv[4];
    for (int r = 0; r < 4; ++r) inv[r] = 1.f / lr[r];
    float* ob = out + ((size_t)b * SEQ_T + q0) * HDIM;
    for (int nt = 0; nt < 8; ++nt)
      for (int r = 0; r < 4; ++r)
        ob[(size_t)(quad * 4 + r) * HDIM + nt * 16 + low] = accv[nt][r] * inv[r];
  } else {
    const int slot = b * ChunkCfg<CS>::SPB + (cum - ChunkCfg<CS>::QB0) + k;
    unsigned short* op = Opart + (size_t)slot * 16384 + (size_t)qt * 16 * 128;
    for (int nt = 0; nt < 8; ++nt)
      for (int r = 0; r < 4; ++r)
        op[(size_t)(quad * 4 + r) * 128 + nt * 16 + low] = f2bf(accv[nt][r]);
    if (low == 0) {
      float* ml = mlpart + (size_t)slot * 256;
      for (int r = 0; r < 4; ++r)
        ml[qt * 16 + quad * 4 + r] = lr[r];   // shared scale: only l needed
    }
  }
}

// ============================ merge (no max, no exp2) ============================
template<int CS>
__global__ __launch_bounds__(256) void merge_k(const unsigned short* __restrict__ Opart,
                                               const float* __restrict__ mlpart,
                                               float* __restrict__ out) {
  const int QB0 = ChunkCfg<CS>::QB0;
  const int rowsPB = (16 - QB0) * 128;
  const int ri  = blockIdx.x * 2 + (threadIdx.x >> 7);
  const int b   = ri / rowsPB;
  const int r2  = ri - b * rowsPB;
  const int qb  = QB0 + (r2 >> 7);
  const int row = r2 & 127;
  const int d   = threadIdx.x & 127;
  const int g   = (2 * qb + 2 + CS - 1) / CS;
  int cum = 0;
  for (int i = 0; i < qb; ++i) cum += (2 * i + 2 + CS - 1) / CS;
  const int s0 = b * ChunkCfg<CS>::SPB + cum - QB0;

  float num = 0.f, den = 0.f;
  for (int k = 0; k < g; ++k) {
    den += mlpart[(size_t)(s0 + k) * 256 + row];
    num += bf2f(Opart[(size_t)(s0 + k) * 16384 + (size_t)row * 128 + d]);
  }
  out[((size_t)b * SEQ_T + qb * 128 + row) * HDIM + d] = num / den;
}

// ============================ no-ws fallback (R4, online softmax) ============================
__global__ __launch_bounds__(512, 4) void attn_fb(const float* __restrict__ x,
                                                  float* __restrict__ out) {
  const int b    = blockIdx.y;
  const int qblk = (int)gridDim.x - 1 - (int)blockIdx.x;
  const int qb0  = qblk << 6;
  const int tid  = threadIdx.x;
  const int wave = tid >> 6;
  const int lane = tid & 63;
  const int low  = lane & 15;
  const int quad = lane >> 4;
  const int qt   = wave & 3;
  const int half = wave >> 2;
  const int q0   = qb0 + (qt << 4);
  __shared__ __align__(16) unsigned char smem[48128];
  unsigned short* Ks = (unsigned short*)smem;
  unsigned short* Vt = (unsigned short*)(smem + 17408);
  unsigned short* Ps = (unsigned short*)(smem + 37888);
  float* Om = (float*)smem;
  float* Ml = (float*)(smem + 33792);
  const float* xb = x + (size_t)b * (SEQ_T * 3 * HDIM);
  const float qs = 0.08838834764831845f * 1.4426950408889634f;
  short8 qa[4];
  {
    const float* qrow = xb + (size_t)(q0 + low) * 384 + 128;
    for (int kc = 0; kc < 4; ++kc) {
      float4v f0 = *(const float4v*)(qrow + kc * 32 + quad * 8);
      float4v f1 = *(const float4v*)(qrow + kc * 32 + quad * 8 + 4);
      uint4v u = { bfpack2(f0[0] * qs, f0[1] * qs), bfpack2(f0[2] * qs, f0[3] * qs),
                   bfpack2(f1[0] * qs, f1[1] * qs), bfpack2(f1[2] * qs, f1[3] * qs) };
      qa[kc] = __builtin_bit_cast(short8, u);
    }
  }
  float4v accv[8];
  for (int i = 0; i < 8; ++i) accv[i] = (float4v){0.f, 0.f, 0.f, 0.f};
  float m_i[4] = {-1e30f, -1e30f, -1e30f, -1e30f};
  float l_i[4] = {0.f, 0.f, 0.f, 0.f};
  const int nsuper = qblk + 1;
  for (int s = 0; s < nsuper; ++s) {
    const int r0 = s << 6;
    __syncthreads();
    for (int i = 0; i < 4; ++i) {
      int f = tid + (i << 9);
      int row = f >> 5;
      int c4 = (f & 31) << 2;
      float4v kf = *(const float4v*)(xb + (size_t)(r0 + row) * 384 + c4);
      *(uint2*)&Ks[(row >> 5) * 4352 + (row & 31) * 136 + c4] =
          make_uint2(bfpack2(kf[0], kf[1]), bfpack2(kf[2], kf[3]));
    }
    {
      int kb = tid >> 5, db = tid & 31;
      int til = kb >> 3, kbl = kb & 7;
      const float* vbase = xb + (size_t)(r0 + 4 * kb) * 384 + 256 + 4 * db;
      float4v v0 = *(const float4v*)(vbase);
      float4v v1 = *(const float4v*)(vbase + 384);
      float4v v2 = *(const float4v*)(vbase + 768);
      float4v v3 = *(const float4v*)(vbase + 1152);
      unsigned short* vv = Vt + til * 5120;
      for (int j = 0; j < 4; ++j) {
        int d = 4 * db + j;
        int pb = ((kbl >> 1) + (d >> 3)) & 3;
        *(uint2*)&vv[d * 40 + pb * 8 + (kbl & 1) * 4] =
            make_uint2(bfpack2(v0[j], v1[j]), bfpack2(v2[j], v3[j]));
      }
    }
    __syncthreads();
    const int c0 = r0 + (half << 5);
    if (c0 <= q0 + 15) {
      const unsigned short* Ksp = Ks + half * 4352;
      const unsigned short* Vtp = Vt + half * 5120;
      float4v s0 = {0.f,0.f,0.f,0.f}, s1 = {0.f,0.f,0.f,0.f};
      for (int kc = 0; kc < 4; ++kc) {
        short8 kf0 = *(const short8*)&Ksp[low * 136 + kc * 32 + quad * 8];
        short8 kf1 = *(const short8*)&Ksp[(16 + low) * 136 + kc * 32 + quad * 8];
        s0 = __builtin_amdgcn_mfma_f32_16x16x32_bf16(qa[kc], kf0, s0, 0, 0, 0);
        s1 = __builtin_amdgcn_mfma_f32_16x16x32_bf16(qa[kc], kf1, s1, 0, 0, 0);
      }
      if (c0 + 31 > q0) {
        for (int r = 0; r < 4; ++r) {
          int qrow = q0 + quad * 4 + r;
          s0[r] = (c0 + low      <= qrow) ? s0[r] : -1e30f;
          s1[r] = (c0 + 16 + low <= qrow) ? s1[r] : -1e30f;
        }
      }
      float rmax[4], alpha[4];
      for (int r = 0; r < 4; ++r) rmax[r] = dpp_max16(fmaxf(s0[r], s1[r]));
      for (int r = 0; r < 4; ++r) {
        float mn = fmaxf(m_i[r], rmax[r]);
        alpha[r] = EXP2F(m_i[r] - mn);
        m_i[r] = mn;
      }
      for (int r = 0; r < 4; ++r) {
        s0[r] = EXP2F(s0[r] - m_i[r]);
        s1[r] = EXP2F(s1[r] - m_i[r]);
      }
      float rs[4];
      for (int r = 0; r < 4; ++r) rs[r] = dpp_sum16(s0[r] + s1[r]);
      for (int r = 0; r < 4; ++r) l_i[r] = l_i[r] * alpha[r] + rs[r];
      for (int nt = 0; nt < 8; ++nt)
        for (int r = 0; r < 4; ++r) accv[nt][r] *= alpha[r];
      unsigned short* pw = Ps + wave * 640;
      for (int r = 0; r < 4; ++r) {
        int row = quad * 4 + r;
        pw[row * 40 + low]      = f2bf(s0[r]);
        pw[row * 40 + 16 + low] = f2bf(s1[r]);
      }
      short8 pa = *(const short8*)&pw[low * 40 + quad * 8];
      for (int nt = 0; nt < 8; ++nt) {
        int d = nt * 16 + low;
        int pb = (quad + (d >> 3)) & 3;
        short8 vf = *(const short8*)&Vtp[d * 40 + pb * 8];
        accv[nt] = __builtin_amdgcn_mfma_f32_16x16x32_bf16(pa, vf, accv[nt], 0, 0, 0);
      }
    }
  }
  __syncthreads();
  if (half == 1) {
    float* om = Om + qt * 2112;
    for (int nt = 0; nt < 8; ++nt)
      for (int r = 0; r < 4; ++r)
        om[(quad * 4 + r) * 132 + nt * 16 + low] = accv[nt][r];
    if (low == 0) {
      for (int r = 0; r < 4; ++r) {
        Ml[qt * 32 + quad * 4 + r]      = m_i[r];
        Ml[qt * 32 + 16 + quad * 4 + r] = l_i[r];
      }
    }
  }
  __syncthreads();
  if (half == 0) {
    float aA[4], aB[4], linv[4];
    for (int r = 0; r < 4; ++r) {
      float mB = Ml[qt * 32 + quad * 4 + r];
      float lB = Ml[qt * 32 + 16 + quad * 4 + r];
      float mN = fmaxf(m_i[r], mB);
      aA[r] = EXP2F(m_i[r] - mN);
      aB[r] = EXP2F(mB - mN);
      linv[r] = 1.f / (l_i[r] * aA[r] + lB * aB[r]);
    }
    const float* om = Om + qt * 2112;
    float* ob = out + ((size_t)b * SEQ_T + q0) * HDIM;
    for (int nt = 0; nt < 8; ++nt)
      for (int r = 0; r < 4; ++r) {
        float o = accv[nt][r] * aA[r] + om[(quad * 4 + r) * 132 + nt * 16 + low] * aB[r];
        ob[(size_t)(quad * 4 + r) * HDIM + nt * 16 + low] = o * linv[r];
      }
  }
}

extern "C" void kernel_launch(void* const* d_in, const int* in_sizes, int n_in,
                              void* d_out, int out_size, void* d_ws, size_t ws_size,
                              hipStream_t stream) {
  const float* x = (const float*)d_in[0];
  float* out = (float*)d_out;
  const size_t PRE = (size_t)NB * NTILES * TILE_SHORTS * 2 * sizeof(unsigned short); // 16 MB

  const size_t OP4 = (size_t)NB * 70 * 16384 * sizeof(unsigned short);   // 36.7 MB
  const size_t ML4 = (size_t)NB * 70 * 256 * sizeof(float);
  const size_t OP8 = (size_t)NB * 36 * 16384 * sizeof(unsigned short);   // 18.9 MB
  const size_t ML8 = (size_t)NB * 36 * 256 * sizeof(float);

  unsigned short* kbuf = (unsigned short*)d_ws;
  unsigned short* vbuf = kbuf + (size_t)NB * NTILES * TILE_SHORTS;

  if (ws_size >= PRE + OP4 + ML4) {
    unsigned short* Opart = (unsigned short*)((char*)d_ws + PRE);
    float*          mlp   = (float*)((char*)d_ws + PRE + OP4);
    hipLaunchKernelGGL(prepass2, dim3(NB * NTILES * 2), dim3(256), 0, stream, x, kbuf, vbuf);
    hipLaunchKernelGGL((attn_chunk_k<4>), dim3(NB * 72), dim3(512), 0, stream,
                       x, kbuf, vbuf, Opart, mlp, out);
    hipLaunchKernelGGL((merge_k<4>), dim3(NB * 14 * 128 / 2), dim3(256), 0, stream,
                       Opart, mlp, out);
  } else if (ws_size >= PRE + OP8 + ML8) {
    unsigned short* Opart = (unsigned short*)((char*)d_ws + PRE);
    float*          mlp   = (float*)((char*)d_ws + PRE + OP8);
    hipLaunchKernelGGL(prepass2, dim3(NB * NTILES * 2), dim3(256), 0, stream, x, kbuf, vbuf);
    hipLaunchKernelGGL((attn_chunk_k<8>), dim3(NB * 40), dim3(512), 0, stream,
                       x, kbuf, vbuf, Opart, mlp, out);
    hipLaunchKernelGGL((merge_k<8>), dim3(NB * 12 * 128 / 2), dim3(256), 0, stream,
                       Opart, mlp, out);
  } else {
    hipLaunchKernelGGL(attn_fb, dim3(SEQ_T / 64, NB), dim3(512), 0, stream, x, out);
  }
}

// Round 10
// 138.979 us; speedup vs baseline: 1.0355x; 1.0228x over previous
//
#include <hip/hip_runtime.h>

#define SEQ_T 2048
#define HDIM  128
#define NB    16
#define NTILES (SEQ_T / 64)          // 32 kv-tiles of 64
#define TILE_SHORTS 8192             // 16 KB per tile (64x128 bf16)

typedef __attribute__((ext_vector_type(8))) short short8;      // 8 bf16 (4 VGPRs)
typedef __attribute__((ext_vector_type(4))) float float4v;
typedef __attribute__((ext_vector_type(4))) unsigned int uint4v;

#define EXP2F(x) __builtin_amdgcn_exp2f(x)

__device__ __forceinline__ unsigned int bfpack2(float a, float b) {
  unsigned int ua = __builtin_bit_cast(unsigned int, a);
  unsigned int ub = __builtin_bit_cast(unsigned int, b);
  return ((ua + 0x8000u) >> 16) | ((ub + 0x8000u) & 0xFFFF0000u);
}
__device__ __forceinline__ unsigned short f2bf(float a) {
  return (unsigned short)((__builtin_bit_cast(unsigned int, a) + 0x8000u) >> 16);
}
__device__ __forceinline__ float bf2f(unsigned short h) {
  unsigned int u = ((unsigned int)h) << 16;
  return __builtin_bit_cast(float, u);
}

__device__ __forceinline__ float dpp_max16(float x) {
  int t;
  t = __builtin_amdgcn_mov_dpp(__builtin_bit_cast(int, x), 0xB1, 0xF, 0xF, true);
  x = fmaxf(x, __builtin_bit_cast(float, t));
  t = __builtin_amdgcn_mov_dpp(__builtin_bit_cast(int, x), 0x4E, 0xF, 0xF, true);
  x = fmaxf(x, __builtin_bit_cast(float, t));
  t = __builtin_amdgcn_mov_dpp(__builtin_bit_cast(int, x), 0x141, 0xF, 0xF, true);
  x = fmaxf(x, __builtin_bit_cast(float, t));
  t = __builtin_amdgcn_mov_dpp(__builtin_bit_cast(int, x), 0x140, 0xF, 0xF, true);
  x = fmaxf(x, __builtin_bit_cast(float, t));
  return x;
}
__device__ __forceinline__ float dpp_sum16(float x) {
  int t;
  t = __builtin_amdgcn_mov_dpp(__builtin_bit_cast(int, x), 0xB1, 0xF, 0xF, true);
  x += __builtin_bit_cast(float, t);
  t = __builtin_amdgcn_mov_dpp(__builtin_bit_cast(int, x), 0x4E, 0xF, 0xF, true);
  x += __builtin_bit_cast(float, t);
  t = __builtin_amdgcn_mov_dpp(__builtin_bit_cast(int, x), 0x141, 0xF, 0xF, true);
  x += __builtin_bit_cast(float, t);
  t = __builtin_amdgcn_mov_dpp(__builtin_bit_cast(int, x), 0x140, 0xF, 0xF, true);
  x += __builtin_bit_cast(float, t);
  return x;
}

// chunks per batch / partial slots per batch for chunk size CS (super-iters).
// R10: CS=5 balanced chunking -> CPB=61 -> 976 blocks <= 1024 co-resident slots
// (4 blocks/CU x 256 CU): the whole grid runs in ONE scheduling round. Chunk k
// of a qb with n=2qb+2 iters covers [k*n/g, (k+1)*n/g), g=ceil(n/5) (sizes 2-5).
template<int CS> struct ChunkCfg;
template<> struct ChunkCfg<5> { static const int CPB = 61, SPB = 59, QB0 = 2; };
template<> struct ChunkCfg<8> { static const int CPB = 40, SPB = 36, QB0 = 4; };

// ============================ prepass (R9: half-tile split) ============================
// Bit-identical kbuf/vbuf images to the R5 prepass. One block per (b, tile, half).
__global__ __launch_bounds__(256) void prepass2(const float* __restrict__ x,
                                                unsigned short* __restrict__ kbuf,
                                                unsigned short* __restrict__ vbuf) {
  const int bid = blockIdx.x;
  const int b   = bid >> 6;            // 64 half-tiles per batch
  const int rem = bid & 63;
  const int t   = rem >> 1;            // 64-kv tile
  const int h   = rem & 1;             // half
  const int tid = threadIdx.x;
  __shared__ __align__(16) unsigned short Klds[4096];  // [32 rows][128 cols]
  __shared__ __align__(16) unsigned short Vlds[4096];  // local d in [0,64): [d][slot][8]

  const float* xb = x + (size_t)b * (SEQ_T * 384) + (size_t)t * 64 * 384;

  // K: rows 32h..32h+31, cols 0..127
  for (int i = 0; i < 4; ++i) {
    int idx = tid + i * 256;                    // 0..1023
    int rl = idx >> 5, c4 = (idx & 31) << 2;
    float4v f = *(const float4v*)(xb + (size_t)(32 * h + rl) * 384 + c4);
    *(uint2*)&Klds[rl * 128 + c4] = make_uint2(bfpack2(f[0], f[1]), bfpack2(f[2], f[3]));
  }
  // V: all 64 rows, cols 64h..64h+63
  {
    int kb = tid >> 4, db2 = tid & 15;          // kb: 16 groups of 4 rows
    int c4 = 64 * h + 4 * db2;
    const float* vb = xb + (size_t)(4 * kb) * 384 + 256 + c4;
    float4v v0 = *(const float4v*)(vb);
    float4v v1 = *(const float4v*)(vb + 384);
    float4v v2 = *(const float4v*)(vb + 768);
    float4v v3 = *(const float4v*)(vb + 1152);
    int sl = ((kb >> 3) << 2) | (kb & 3);       // permuted slot (R5 mapping)
    int o  = ((kb >> 2) & 1) * 4;
    for (int j = 0; j < 4; ++j) {
      int d = c4 + j;
      *(uint2*)&Vlds[(d - 64 * h) * 64 + ((sl + d) & 7) * 8 + o] =
          make_uint2(bfpack2(v0[j], v1[j]), bfpack2(v2[j], v3[j]));
    }
  }
  __syncthreads();

  unsigned short* kdst = kbuf + (size_t)(b * NTILES + t) * TILE_SHORTS;
  unsigned short* vdst = vbuf + (size_t)(b * NTILES + t) * TILE_SHORTS;
  for (int i = 0; i < 2; ++i) {
    int nloc = tid + i * 256;                   // 0..511
    int n = 512 * h + nloc;                     // global unit
    int rl = nloc >> 4, pu = nloc & 15;
    int u = (pu - (32 * h + rl)) & 15;          // == (pu - rl) & 15 since 32h%16==0
    *(uint4v*)&kdst[n * 8] = *(const uint4v*)&Klds[rl * 128 + u * 8];
    *(uint4v*)&vdst[n * 8] = *(const uint4v*)&Vlds[nloc * 8];  // final image
  }
}

// ============================ chunked attention ============================
// R5 PROVEN COMPUTE BODY (42.5us): 128-row blocks, 8 waves, 4 blocks/CU,
// two-barrier T14 reg-staged prefetch, swapped-QK (P lane-local), permuted V
// image (PV = one rot-swizzled ds_read_b128).
// R10: CS=5 balanced chunks (976 blocks -> single scheduling round) + LPT
// dispatch reversal (c = CPB-1-c: longest qb=15 chunks launch first; tail, if
// any, is the short qb=0/1 chunks). Occupancy 29% avg + 1152>1024 blocks
// indicated a sparse straggler round of the LONGEST chunks under the old
// ascending-qb order.
// LEDGER:
//  * single-barrier global_load_lds DMA: corrupted TWICE — banned.
//  * R4 V b64 pair-read: 4-way bank conflict — retired.
//  * R6 256-row/2-blocks-per-CU: +24% — inter-block TLP (4 blocks/CU) is the
//    dominant latency-hiding resource; never trade it away.
//  * R7 T5 setprio around MFMA clusters: −12% (starves staging waves) — retired.
//  * R8 KVBLK=32 V half-image: conflicts 2.13M->4.26M — the 8-slot/64-short
//    rotation is load-bearing; retired.
// launch_bounds(512,4): (512,8) collapses the allocator (prior session R7).
template<int CS>
__global__ __launch_bounds__(512, 4) void attn_chunk_k(const float* __restrict__ x,
                                                       const unsigned short* __restrict__ kbuf,
                                                       const unsigned short* __restrict__ vbuf,
                                                       unsigned short* __restrict__ Opart,
                                                       float* __restrict__ mlpart,
                                                       float* __restrict__ out) {
  const int f = blockIdx.x;
  const int b = f / ChunkCfg<CS>::CPB;
  int c = f - b * ChunkCfg<CS>::CPB;
  c = ChunkCfg<CS>::CPB - 1 - c;          // LPT: longest chunks (high qb) first
  int qb = 0, cum = 0;
  for (;;) {
    int gg = (2 * qb + 2 + CS - 1) / CS;
    if (c < cum + gg) break;
    cum += gg; ++qb;
  }
  const int n = 2 * qb + 2;
  const int g = (n + CS - 1) / CS;
  const int k = c - cum;
  const int sBeg = (k * n) / g;            // balanced split (sizes 2..CS)
  const int sEnd = ((k + 1) * n) / g;

  const int tid  = threadIdx.x;
  const int qt   = tid >> 6;
  const int lane = tid & 63;
  const int low  = lane & 15;
  const int quad = lane >> 4;
  const int q0   = qb * 128 + qt * 16;

  __shared__ __align__(16) unsigned char smem[32768];    // K tile + V tile only
  unsigned short* Ks = (unsigned short*)smem;            // 16 KB swizzled K tile
  unsigned short* Vt = (unsigned short*)(smem + 16384);  // 16 KB swizzled V^T tile

  const float* xb = x + (size_t)b * (SEQ_T * 3 * HDIM);
  const unsigned short* kt = kbuf + (size_t)b * NTILES * TILE_SHORTS;
  const unsigned short* vt = vbuf + (size_t)b * NTILES * TILE_SHORTS;

  const float qs = 0.08838834764831845f * 1.4426950408889634f;
  short8 qa[4];
  {
    const float* qrow = xb + (size_t)(q0 + low) * 384 + 128;
    for (int kc = 0; kc < 4; ++kc) {
      float4v f0 = *(const float4v*)(qrow + kc * 32 + quad * 8);
      float4v f1 = *(const float4v*)(qrow + kc * 32 + quad * 8 + 4);
      uint4v u = { bfpack2(f0[0] * qs, f0[1] * qs), bfpack2(f0[2] * qs, f0[3] * qs),
                   bfpack2(f1[0] * qs, f1[1] * qs), bfpack2(f1[2] * qs, f1[3] * qs) };
      qa[kc] = __builtin_bit_cast(short8, u);
    }
  }

  float4v accv[8];
  for (int i = 0; i < 8; ++i) accv[i] = (float4v){0.f, 0.f, 0.f, 0.f};
  float l = 0.f;                         // per-lane: q-row = low

  const int ch = qt * 2;

  // T14 staging registers: this wave's 2 K-chunks + 2 V-chunks, 16B/lane each
  uint4v kr0, kr1, vr0, vr1;
  {
    const unsigned short* ksrc = kt + (size_t)sBeg * TILE_SHORTS;
    const unsigned short* vsrc = vt + (size_t)sBeg * TILE_SHORTS;
    kr0 = *(const uint4v*)(ksrc + (size_t)ch * 512 + lane * 8);
    kr1 = *(const uint4v*)(ksrc + (size_t)(ch + 1) * 512 + lane * 8);
    vr0 = *(const uint4v*)(vsrc + (size_t)ch * 512 + lane * 8);
    vr1 = *(const uint4v*)(vsrc + (size_t)(ch + 1) * 512 + lane * 8);
  }

  for (int s = sBeg; s < sEnd; ++s) {
    __syncthreads();   // all waves done reading previous tile; prev prefetch drained

    *(uint4v*)&Ks[(size_t)ch * 512 + lane * 8]       = kr0;
    *(uint4v*)&Ks[(size_t)(ch + 1) * 512 + lane * 8] = kr1;
    *(uint4v*)&Vt[(size_t)ch * 512 + lane * 8]       = vr0;
    *(uint4v*)&Vt[(size_t)(ch + 1) * 512 + lane * 8] = vr1;

    __syncthreads();   // tile-s image visible to all waves

    if (s + 1 < sEnd) {   // prefetch next tile; latency hides under compute below
      const unsigned short* ksrc = kt + (size_t)(s + 1) * TILE_SHORTS;
      const unsigned short* vsrc = vt + (size_t)(s + 1) * TILE_SHORTS;
      kr0 = *(const uint4v*)(ksrc + (size_t)ch * 512 + lane * 8);
      kr1 = *(const uint4v*)(ksrc + (size_t)(ch + 1) * 512 + lane * 8);
      vr0 = *(const uint4v*)(vsrc + (size_t)ch * 512 + lane * 8);
      vr1 = *(const uint4v*)(vsrc + (size_t)(ch + 1) * 512 + lane * 8);
    }

    for (int h = 0; h < 2; ++h) {
      const int c0 = s * 64 + h * 32;
      if (c0 > q0 + 15) continue;
      const int Ra = (h << 5) + low;
      const int Rb = Ra + 16;
      float4v s0 = {0.f,0.f,0.f,0.f}, s1 = {0.f,0.f,0.f,0.f};
      for (int kc = 0; kc < 4; ++kc) {
        short8 kf0 = *(const short8*)&Ks[Ra * 128 + (((kc * 4 + quad) + Ra) & 15) * 8];
        short8 kf1 = *(const short8*)&Ks[Rb * 128 + (((kc * 4 + quad) + Rb) & 15) * 8];
        // SWAPPED: S^T = K . Q^T -> lane(low,quad) reg r = P[q0+low][c0 + quad*4 + r]
        s0 = __builtin_amdgcn_mfma_f32_16x16x32_bf16(kf0, qa[kc], s0, 0, 0, 0);
        s1 = __builtin_amdgcn_mfma_f32_16x16x32_bf16(kf1, qa[kc], s1, 0, 0, 0);
      }
      if (c0 + 31 > q0) {
        const int qrow = q0 + low;
        for (int r = 0; r < 4; ++r) {
          s0[r] = (c0 + quad * 4 + r      <= qrow) ? s0[r] : -1e30f;
          s1[r] = (c0 + 16 + quad * 4 + r <= qrow) ? s1[r] : -1e30f;
        }
      }
      // max-free softmax: P = exp2(s); l accumulates lane-locally (q-row = low)
      for (int r = 0; r < 4; ++r) {
        s0[r] = EXP2F(s0[r]);               // masked -1e30 -> 0
        s1[r] = EXP2F(s1[r]);
      }
      l += (s0[0] + s0[1]) + (s0[2] + s0[3]) + (s1[0] + s1[1]) + (s1[2] + s1[3]);

      // P A-fragment, k-permuted: pi(p=8q+j) = 4q+(j&3)+16*(j>=4) — in registers
      uint4v pu = { bfpack2(s0[0], s0[1]), bfpack2(s0[2], s0[3]),
                    bfpack2(s1[0], s1[1]), bfpack2(s1[2], s1[3]) };
      short8 pa = __builtin_bit_cast(short8, pu);

      // V B-fragment: slot sl=4h+quad of the permuted image = one b128 read
      const int sl = (h << 2) + quad;
      for (int nt = 0; nt < 8; ++nt) {
        int d = nt * 16 + low;
        short8 vf = *(const short8*)&Vt[d * 64 + ((sl + d) & 7) * 8];
        accv[nt] = __builtin_amdgcn_mfma_f32_16x16x32_bf16(pa, vf, accv[nt], 0, 0, 0);
      }
    }
  }

  // reduce l across quads (lanes low, low+16, low+32, low+48 share q-row = low)
  l += __shfl_xor(l, 16);
  l += __shfl_xor(l, 32);
  // redistribute to accv row layout: row = quad*4 + r
  float lr[4];
  for (int r = 0; r < 4; ++r) lr[r] = __shfl(l, quad * 4 + r);

  if (g == 1) {
    float inv[4];
    for (int r = 0; r < 4; ++r) inv[r] = 1.f / lr[r];
    float* ob = out + ((size_t)b * SEQ_T + q0) * HDIM;
    for (int nt = 0; nt < 8; ++nt)
      for (int r = 0; r < 4; ++r)
        ob[(size_t)(quad * 4 + r) * HDIM + nt * 16 + low] = accv[nt][r] * inv[r];
  } else {
    const int slot = b * ChunkCfg<CS>::SPB + (cum - ChunkCfg<CS>::QB0) + k;
    unsigned short* op = Opart + (size_t)slot * 16384 + (size_t)qt * 16 * 128;
    for (int nt = 0; nt < 8; ++nt)
      for (int r = 0; r < 4; ++r)
        op[(size_t)(quad * 4 + r) * 128 + nt * 16 + low] = f2bf(accv[nt][r]);
    if (low == 0) {
      float* ml = mlpart + (size_t)slot * 256;
      for (int r = 0; r < 4; ++r)
        ml[qt * 16 + quad * 4 + r] = lr[r];   // shared scale: only l needed
    }
  }
}

// ============================ merge (no max, no exp2) ============================
// Boundary-agnostic: only the chunk COUNT per qb matters (same ceil formula).
template<int CS>
__global__ __launch_bounds__(256) void merge_k(const unsigned short* __restrict__ Opart,
                                               const float* __restrict__ mlpart,
                                               float* __restrict__ out) {
  const int QB0 = ChunkCfg<CS>::QB0;
  const int rowsPB = (16 - QB0) * 128;
  const int ri  = blockIdx.x * 2 + (threadIdx.x >> 7);
  const int b   = ri / rowsPB;
  const int r2  = ri - b * rowsPB;
  const int qb  = QB0 + (r2 >> 7);
  const int row = r2 & 127;
  const int d   = threadIdx.x & 127;
  const int g   = (2 * qb + 2 + CS - 1) / CS;
  int cum = 0;
  for (int i = 0; i < qb; ++i) cum += (2 * i + 2 + CS - 1) / CS;
  const int s0 = b * ChunkCfg<CS>::SPB + cum - QB0;

  float num = 0.f, den = 0.f;
  for (int k = 0; k < g; ++k) {
    den += mlpart[(size_t)(s0 + k) * 256 + row];
    num += bf2f(Opart[(size_t)(s0 + k) * 16384 + (size_t)row * 128 + d]);
  }
  out[((size_t)b * SEQ_T + qb * 128 + row) * HDIM + d] = num / den;
}

// ============================ no-ws fallback (R4, online softmax) ============================
__global__ __launch_bounds__(512, 4) void attn_fb(const float* __restrict__ x,
                                                  float* __restrict__ out) {
  const int b    = blockIdx.y;
  const int qblk = (int)gridDim.x - 1 - (int)blockIdx.x;
  const int qb0  = qblk << 6;
  const int tid  = threadIdx.x;
  const int wave = tid >> 6;
  const int lane = tid & 63;
  const int low  = lane & 15;
  const int quad = lane >> 4;
  const int qt   = wave & 3;
  const int half = wave >> 2;
  const int q0   = qb0 + (qt << 4);
  __shared__ __align__(16) unsigned char smem[48128];
  unsigned short* Ks = (unsigned short*)smem;
  unsigned short* Vt = (unsigned short*)(smem + 17408);
  unsigned short* Ps = (unsigned short*)(smem + 37888);
  float* Om = (float*)smem;
  float* Ml = (float*)(smem + 33792);
  const float* xb = x + (size_t)b * (SEQ_T * 3 * HDIM);
  const float qs = 0.08838834764831845f * 1.4426950408889634f;
  short8 qa[4];
  {
    const float* qrow = xb + (size_t)(q0 + low) * 384 + 128;
    for (int kc = 0; kc < 4; ++kc) {
      float4v f0 = *(const float4v*)(qrow + kc * 32 + quad * 8);
      float4v f1 = *(const float4v*)(qrow + kc * 32 + quad * 8 + 4);
      uint4v u = { bfpack2(f0[0] * qs, f0[1] * qs), bfpack2(f0[2] * qs, f0[3] * qs),
                   bfpack2(f1[0] * qs, f1[1] * qs), bfpack2(f1[2] * qs, f1[3] * qs) };
      qa[kc] = __builtin_bit_cast(short8, u);
    }
  }
  float4v accv[8];
  for (int i = 0; i < 8; ++i) accv[i] = (float4v){0.f, 0.f, 0.f, 0.f};
  float m_i[4] = {-1e30f, -1e30f, -1e30f, -1e30f};
  float l_i[4] = {0.f, 0.f, 0.f, 0.f};
  const int nsuper = qblk + 1;
  for (int s = 0; s < nsuper; ++s) {
    const int r0 = s << 6;
    __syncthreads();
    for (int i = 0; i < 4; ++i) {
      int f = tid + (i << 9);
      int row = f >> 5;
      int c4 = (f & 31) << 2;
      float4v kf = *(const float4v*)(xb + (size_t)(r0 + row) * 384 + c4);
      *(uint2*)&Ks[(row >> 5) * 4352 + (row & 31) * 136 + c4] =
          make_uint2(bfpack2(kf[0], kf[1]), bfpack2(kf[2], kf[3]));
    }
    {
      int kb = tid >> 5, db = tid & 31;
      int til = kb >> 3, kbl = kb & 7;
      const float* vbase = xb + (size_t)(r0 + 4 * kb) * 384 + 256 + 4 * db;
      float4v v0 = *(const float4v*)(vbase);
      float4v v1 = *(const float4v*)(vbase + 384);
      float4v v2 = *(const float4v*)(vbase + 768);
      float4v v3 = *(const float4v*)(vbase + 1152);
      unsigned short* vv = Vt + til * 5120;
      for (int j = 0; j < 4; ++j) {
        int d = 4 * db + j;
        int pb = ((kbl >> 1) + (d >> 3)) & 3;
        *(uint2*)&vv[d * 40 + pb * 8 + (kbl & 1) * 4] =
            make_uint2(bfpack2(v0[j], v1[j]), bfpack2(v2[j], v3[j]));
      }
    }
    __syncthreads();
    const int c0 = r0 + (half << 5);
    if (c0 <= q0 + 15) {
      const unsigned short* Ksp = Ks + half * 4352;
      const unsigned short* Vtp = Vt + half * 5120;
      float4v s0 = {0.f,0.f,0.f,0.f}, s1 = {0.f,0.f,0.f,0.f};
      for (int kc = 0; kc < 4; ++kc) {
        short8 kf0 = *(const short8*)&Ksp[low * 136 + kc * 32 + quad * 8];
        short8 kf1 = *(const short8*)&Ksp[(16 + low) * 136 + kc * 32 + quad * 8];
        s0 = __builtin_amdgcn_mfma_f32_16x16x32_bf16(qa[kc], kf0, s0, 0, 0, 0);
        s1 = __builtin_amdgcn_mfma_f32_16x16x32_bf16(qa[kc], kf1, s1, 0, 0, 0);
      }
      if (c0 + 31 > q0) {
        for (int r = 0; r < 4; ++r) {
          int qrow = q0 + quad * 4 + r;
          s0[r] = (c0 + low      <= qrow) ? s0[r] : -1e30f;
          s1[r] = (c0 + 16 + low <= qrow) ? s1[r] : -1e30f;
        }
      }
      float rmax[4], alpha[4];
      for (int r = 0; r < 4; ++r) rmax[r] = dpp_max16(fmaxf(s0[r], s1[r]));
      for (int r = 0; r < 4; ++r) {
        float mn = fmaxf(m_i[r], rmax[r]);
        alpha[r] = EXP2F(m_i[r] - mn);
        m_i[r] = mn;
      }
      for (int r = 0; r < 4; ++r) {
        s0[r] = EXP2F(s0[r] - m_i[r]);
        s1[r] = EXP2F(s1[r] - m_i[r]);
      }
      float rs[4];
      for (int r = 0; r < 4; ++r) rs[r] = dpp_sum16(s0[r] + s1[r]);
      for (int r = 0; r < 4; ++r) l_i[r] = l_i[r] * alpha[r] + rs[r];
      for (int nt = 0; nt < 8; ++nt)
        for (int r = 0; r < 4; ++r) accv[nt][r] *= alpha[r];
      unsigned short* pw = Ps + wave * 640;
      for (int r = 0; r < 4; ++r) {
        int row = quad * 4 + r;
        pw[row * 40 + low]      = f2bf(s0[r]);
        pw[row * 40 + 16 + low] = f2bf(s1[r]);
      }
      short8 pa = *(const short8*)&pw[low * 40 + quad * 8];
      for (int nt = 0; nt < 8; ++nt) {
        int d = nt * 16 + low;
        int pb = (quad + (d >> 3)) & 3;
        short8 vf = *(const short8*)&Vtp[d * 40 + pb * 8];
        accv[nt] = __builtin_amdgcn_mfma_f32_16x16x32_bf16(pa, vf, accv[nt], 0, 0, 0);
      }
    }
  }
  __syncthreads();
  if (half == 1) {
    float* om = Om + qt * 2112;
    for (int nt = 0; nt < 8; ++nt)
      for (int r = 0; r < 4; ++r)
        om[(quad * 4 + r) * 132 + nt * 16 + low] = accv[nt][r];
    if (low == 0) {
      for (int r = 0; r < 4; ++r) {
        Ml[qt * 32 + quad * 4 + r]      = m_i[r];
        Ml[qt * 32 + 16 + quad * 4 + r] = l_i[r];
      }
    }
  }
  __syncthreads();
  if (half == 0) {
    float aA[4], aB[4], linv[4];
    for (int r = 0; r < 4; ++r) {
      float mB = Ml[qt * 32 + quad * 4 + r];
      float lB = Ml[qt * 32 + 16 + quad * 4 + r];
      float mN = fmaxf(m_i[r], mB);
      aA[r] = EXP2F(m_i[r] - mN);
      aB[r] = EXP2F(mB - mN);
      linv[r] = 1.f / (l_i[r] * aA[r] + lB * aB[r]);
    }
    const float* om = Om + qt * 2112;
    float* ob = out + ((size_t)b * SEQ_T + q0) * HDIM;
    for (int nt = 0; nt < 8; ++nt)
      for (int r = 0; r < 4; ++r) {
        float o = accv[nt][r] * aA[r] + om[(quad * 4 + r) * 132 + nt * 16 + low] * aB[r];
        ob[(size_t)(quad * 4 + r) * HDIM + nt * 16 + low] = o * linv[r];
      }
  }
}

extern "C" void kernel_launch(void* const* d_in, const int* in_sizes, int n_in,
                              void* d_out, int out_size, void* d_ws, size_t ws_size,
                              hipStream_t stream) {
  const float* x = (const float*)d_in[0];
  float* out = (float*)d_out;
  const size_t PRE = (size_t)NB * NTILES * TILE_SHORTS * 2 * sizeof(unsigned short); // 16 MB

  // thresholds unchanged (CS=5 needs 59 slots < the 70-slot CS=4 allocation)
  const size_t OP4 = (size_t)NB * 70 * 16384 * sizeof(unsigned short);   // 36.7 MB
  const size_t ML4 = (size_t)NB * 70 * 256 * sizeof(float);
  const size_t OP8 = (size_t)NB * 36 * 16384 * sizeof(unsigned short);   // 18.9 MB
  const size_t ML8 = (size_t)NB * 36 * 256 * sizeof(float);

  unsigned short* kbuf = (unsigned short*)d_ws;
  unsigned short* vbuf = kbuf + (size_t)NB * NTILES * TILE_SHORTS;

  if (ws_size >= PRE + OP4 + ML4) {
    unsigned short* Opart = (unsigned short*)((char*)d_ws + PRE);
    float*          mlp   = (float*)((char*)d_ws + PRE + OP4);
    hipLaunchKernelGGL(prepass2, dim3(NB * NTILES * 2), dim3(256), 0, stream, x, kbuf, vbuf);
    hipLaunchKernelGGL((attn_chunk_k<5>), dim3(NB * 61), dim3(512), 0, stream,
                       x, kbuf, vbuf, Opart, mlp, out);
    hipLaunchKernelGGL((merge_k<5>), dim3(NB * 14 * 128 / 2), dim3(256), 0, stream,
                       Opart, mlp, out);
  } else if (ws_size >= PRE + OP8 + ML8) {
    unsigned short* Opart = (unsigned short*)((char*)d_ws + PRE);
    float*          mlp   = (float*)((char*)d_ws + PRE + OP8);
    hipLaunchKernelGGL(prepass2, dim3(NB * NTILES * 2), dim3(256), 0, stream, x, kbuf, vbuf);
    hipLaunchKernelGGL((attn_chunk_k<8>), dim3(NB * 40), dim3(512), 0, stream,
                       x, kbuf, vbuf, Opart, mlp, out);
    hipLaunchKernelGGL((merge_k<8>), dim3(NB * 12 * 128 / 2), dim3(256), 0, stream,
                       Opart, mlp, out);
  } else {
    hipLaunchKernelGGL(attn_fb, dim3(SEQ_T / 64, NB), dim3(512), 0, stream, x, out);
  }
}

// Round 11
// 136.201 us; speedup vs baseline: 1.0566x; 1.0204x over previous
//
#include <hip/hip_runtime.h>

#define SEQ_T 2048
#define HDIM  128
#define NB    16
#define NTILES (SEQ_T / 64)          // 32 kv-tiles of 64
#define TILE_SHORTS 8192             // 16 KB per tile (64x128 bf16)

typedef __attribute__((ext_vector_type(8))) short short8;      // 8 bf16 (4 VGPRs)
typedef __attribute__((ext_vector_type(4))) float float4v;
typedef __attribute__((ext_vector_type(4))) unsigned int uint4v;

#define EXP2F(x) __builtin_amdgcn_exp2f(x)

__device__ __forceinline__ unsigned int bfpack2(float a, float b) {
  unsigned int ua = __builtin_bit_cast(unsigned int, a);
  unsigned int ub = __builtin_bit_cast(unsigned int, b);
  return ((ua + 0x8000u) >> 16) | ((ub + 0x8000u) & 0xFFFF0000u);
}
__device__ __forceinline__ unsigned short f2bf(float a) {
  return (unsigned short)((__builtin_bit_cast(unsigned int, a) + 0x8000u) >> 16);
}
__device__ __forceinline__ float bf2f(unsigned short h) {
  unsigned int u = ((unsigned int)h) << 16;
  return __builtin_bit_cast(float, u);
}

__device__ __forceinline__ float dpp_max16(float x) {
  int t;
  t = __builtin_amdgcn_mov_dpp(__builtin_bit_cast(int, x), 0xB1, 0xF, 0xF, true);
  x = fmaxf(x, __builtin_bit_cast(float, t));
  t = __builtin_amdgcn_mov_dpp(__builtin_bit_cast(int, x), 0x4E, 0xF, 0xF, true);
  x = fmaxf(x, __builtin_bit_cast(float, t));
  t = __builtin_amdgcn_mov_dpp(__builtin_bit_cast(int, x), 0x141, 0xF, 0xF, true);
  x = fmaxf(x, __builtin_bit_cast(float, t));
  t = __builtin_amdgcn_mov_dpp(__builtin_bit_cast(int, x), 0x140, 0xF, 0xF, true);
  x = fmaxf(x, __builtin_bit_cast(float, t));
  return x;
}
__device__ __forceinline__ float dpp_sum16(float x) {
  int t;
  t = __builtin_amdgcn_mov_dpp(__builtin_bit_cast(int, x), 0xB1, 0xF, 0xF, true);
  x += __builtin_bit_cast(float, t);
  t = __builtin_amdgcn_mov_dpp(__builtin_bit_cast(int, x), 0x4E, 0xF, 0xF, true);
  x += __builtin_bit_cast(float, t);
  t = __builtin_amdgcn_mov_dpp(__builtin_bit_cast(int, x), 0x141, 0xF, 0xF, true);
  x += __builtin_bit_cast(float, t);
  t = __builtin_amdgcn_mov_dpp(__builtin_bit_cast(int, x), 0x140, 0xF, 0xF, true);
  x += __builtin_bit_cast(float, t);
  return x;
}

// chunks per batch / partial slots per batch for chunk size CS (super-iters).
// CS=5 balanced chunking -> CPB=61 -> 976 blocks <= 1024 co-resident slots:
// whole grid runs in ONE scheduling round (R10 win).
template<int CS> struct ChunkCfg;
template<> struct ChunkCfg<5> { static const int CPB = 61, SPB = 59, QB0 = 2; };
template<> struct ChunkCfg<8> { static const int CPB = 40, SPB = 36, QB0 = 4; };

// ============================ prepass (R9: half-tile split) ============================
// Bit-identical kbuf/vbuf images to the R5 prepass. One block per (b, tile, half).
__global__ __launch_bounds__(256) void prepass2(const float* __restrict__ x,
                                                unsigned short* __restrict__ kbuf,
                                                unsigned short* __restrict__ vbuf) {
  const int bid = blockIdx.x;
  const int b   = bid >> 6;            // 64 half-tiles per batch
  const int rem = bid & 63;
  const int t   = rem >> 1;            // 64-kv tile
  const int h   = rem & 1;             // half
  const int tid = threadIdx.x;
  __shared__ __align__(16) unsigned short Klds[4096];  // [32 rows][128 cols]
  __shared__ __align__(16) unsigned short Vlds[4096];  // local d in [0,64): [d][slot][8]

  const float* xb = x + (size_t)b * (SEQ_T * 384) + (size_t)t * 64 * 384;

  // K: rows 32h..32h+31, cols 0..127
  for (int i = 0; i < 4; ++i) {
    int idx = tid + i * 256;                    // 0..1023
    int rl = idx >> 5, c4 = (idx & 31) << 2;
    float4v f = *(const float4v*)(xb + (size_t)(32 * h + rl) * 384 + c4);
    *(uint2*)&Klds[rl * 128 + c4] = make_uint2(bfpack2(f[0], f[1]), bfpack2(f[2], f[3]));
  }
  // V: all 64 rows, cols 64h..64h+63
  {
    int kb = tid >> 4, db2 = tid & 15;          // kb: 16 groups of 4 rows
    int c4 = 64 * h + 4 * db2;
    const float* vb = xb + (size_t)(4 * kb) * 384 + 256 + c4;
    float4v v0 = *(const float4v*)(vb);
    float4v v1 = *(const float4v*)(vb + 384);
    float4v v2 = *(const float4v*)(vb + 768);
    float4v v3 = *(const float4v*)(vb + 1152);
    int sl = ((kb >> 3) << 2) | (kb & 3);       // permuted slot (R5 mapping)
    int o  = ((kb >> 2) & 1) * 4;
    for (int j = 0; j < 4; ++j) {
      int d = c4 + j;
      *(uint2*)&Vlds[(d - 64 * h) * 64 + ((sl + d) & 7) * 8 + o] =
          make_uint2(bfpack2(v0[j], v1[j]), bfpack2(v2[j], v3[j]));
    }
  }
  __syncthreads();

  unsigned short* kdst = kbuf + (size_t)(b * NTILES + t) * TILE_SHORTS;
  unsigned short* vdst = vbuf + (size_t)(b * NTILES + t) * TILE_SHORTS;
  for (int i = 0; i < 2; ++i) {
    int nloc = tid + i * 256;                   // 0..511
    int n = 512 * h + nloc;                     // global unit
    int rl = nloc >> 4, pu = nloc & 15;
    int u = (pu - (32 * h + rl)) & 15;          // == (pu - rl) & 15 since 32h%16==0
    *(uint4v*)&kdst[n * 8] = *(const uint4v*)&Klds[rl * 128 + u * 8];
    *(uint4v*)&vdst[n * 8] = *(const uint4v*)&Vlds[nloc * 8];  // final image
  }
}

// ============================ chunked attention ============================
// R5 PROVEN COMPUTE BODY + R10 CS=5 single-round packing + R11 (this round):
// T1 XCD-aware placement. blockIdx round-robins XCDs (bid & 7 = XCD); map
// XCD x -> batches {x, x+8} so each XCD's 4MB L2 holds its two batches' whole
// K/V image (~2MB) -> tile re-reads become L2 hits, shortening the staging
// latency the 1-deep prefetch must hide. 976 = 8 XCD x 122 blocks, uniform.
// LEDGER:
//  * single-barrier global_load_lds DMA: corrupted TWICE — banned.
//  * R4 V b64 pair-read: 4-way bank conflict — retired.
//  * R6 256-row/2-blocks-per-CU: +24% — inter-block TLP (4 blocks/CU) is the
//    dominant latency-hiding resource; never trade it away.
//  * R7 T5 setprio around MFMA clusters: −12% (starves staging waves) — retired.
//  * R8 KVBLK=32 V half-image: conflicts 2.13M->4.26M — retired.
//  * Residual decomposition (R10 counters): 2x 256MiB harness poison fills at
//    80% HBM peak ≈ 84us of every timed iteration — fixed cost, already at
//    their own roofline. Controllable budget = attn + prepass + merge ≈ 55us.
// launch_bounds(512,4): (512,8) collapses the allocator (prior session R7).
template<int CS>
__global__ __launch_bounds__(512, 4) void attn_chunk_k(const float* __restrict__ x,
                                                       const unsigned short* __restrict__ kbuf,
                                                       const unsigned short* __restrict__ vbuf,
                                                       unsigned short* __restrict__ Opart,
                                                       float* __restrict__ mlpart,
                                                       float* __restrict__ out) {
  const int f = blockIdx.x;
  // T1: XCD x (= f & 7, HW round-robin) serves batches {x, x+8}
  const int x7   = f & 7;
  const int j    = f >> 3;                       // 0 .. 2*CPB-1
  const int hi   = (j >= ChunkCfg<CS>::CPB) ? 1 : 0;
  const int b    = x7 + 8 * hi;
  int c = j - hi * ChunkCfg<CS>::CPB;
  c = ChunkCfg<CS>::CPB - 1 - c;                 // LPT: longest chunks first
  int qb = 0, cum = 0;
  for (;;) {
    int gg = (2 * qb + 2 + CS - 1) / CS;
    if (c < cum + gg) break;
    cum += gg; ++qb;
  }
  const int n = 2 * qb + 2;
  const int g = (n + CS - 1) / CS;
  const int k = c - cum;
  const int sBeg = (k * n) / g;            // balanced split (sizes 2..CS)
  const int sEnd = ((k + 1) * n) / g;

  const int tid  = threadIdx.x;
  const int qt   = tid >> 6;
  const int lane = tid & 63;
  const int low  = lane & 15;
  const int quad = lane >> 4;
  const int q0   = qb * 128 + qt * 16;

  __shared__ __align__(16) unsigned char smem[32768];    // K tile + V tile only
  unsigned short* Ks = (unsigned short*)smem;            // 16 KB swizzled K tile
  unsigned short* Vt = (unsigned short*)(smem + 16384);  // 16 KB swizzled V^T tile

  const float* xb = x + (size_t)b * (SEQ_T * 3 * HDIM);
  const unsigned short* kt = kbuf + (size_t)b * NTILES * TILE_SHORTS;
  const unsigned short* vt = vbuf + (size_t)b * NTILES * TILE_SHORTS;

  const float qs = 0.08838834764831845f * 1.4426950408889634f;
  short8 qa[4];
  {
    const float* qrow = xb + (size_t)(q0 + low) * 384 + 128;
    for (int kc = 0; kc < 4; ++kc) {
      float4v f0 = *(const float4v*)(qrow + kc * 32 + quad * 8);
      float4v f1 = *(const float4v*)(qrow + kc * 32 + quad * 8 + 4);
      uint4v u = { bfpack2(f0[0] * qs, f0[1] * qs), bfpack2(f0[2] * qs, f0[3] * qs),
                   bfpack2(f1[0] * qs, f1[1] * qs), bfpack2(f1[2] * qs, f1[3] * qs) };
      qa[kc] = __builtin_bit_cast(short8, u);
    }
  }

  float4v accv[8];
  for (int i = 0; i < 8; ++i) accv[i] = (float4v){0.f, 0.f, 0.f, 0.f};
  float l = 0.f;                         // per-lane: q-row = low

  const int ch = qt * 2;

  // T14 staging registers: this wave's 2 K-chunks + 2 V-chunks, 16B/lane each
  uint4v kr0, kr1, vr0, vr1;
  {
    const unsigned short* ksrc = kt + (size_t)sBeg * TILE_SHORTS;
    const unsigned short* vsrc = vt + (size_t)sBeg * TILE_SHORTS;
    kr0 = *(const uint4v*)(ksrc + (size_t)ch * 512 + lane * 8);
    kr1 = *(const uint4v*)(ksrc + (size_t)(ch + 1) * 512 + lane * 8);
    vr0 = *(const uint4v*)(vsrc + (size_t)ch * 512 + lane * 8);
    vr1 = *(const uint4v*)(vsrc + (size_t)(ch + 1) * 512 + lane * 8);
  }

  for (int s = sBeg; s < sEnd; ++s) {
    __syncthreads();   // all waves done reading previous tile; prev prefetch drained

    *(uint4v*)&Ks[(size_t)ch * 512 + lane * 8]       = kr0;
    *(uint4v*)&Ks[(size_t)(ch + 1) * 512 + lane * 8] = kr1;
    *(uint4v*)&Vt[(size_t)ch * 512 + lane * 8]       = vr0;
    *(uint4v*)&Vt[(size_t)(ch + 1) * 512 + lane * 8] = vr1;

    __syncthreads();   // tile-s image visible to all waves

    if (s + 1 < sEnd) {   // prefetch next tile; latency hides under compute below
      const unsigned short* ksrc = kt + (size_t)(s + 1) * TILE_SHORTS;
      const unsigned short* vsrc = vt + (size_t)(s + 1) * TILE_SHORTS;
      kr0 = *(const uint4v*)(ksrc + (size_t)ch * 512 + lane * 8);
      kr1 = *(const uint4v*)(ksrc + (size_t)(ch + 1) * 512 + lane * 8);
      vr0 = *(const uint4v*)(vsrc + (size_t)ch * 512 + lane * 8);
      vr1 = *(const uint4v*)(vsrc + (size_t)(ch + 1) * 512 + lane * 8);
    }

    for (int h = 0; h < 2; ++h) {
      const int c0 = s * 64 + h * 32;
      if (c0 > q0 + 15) continue;
      const int Ra = (h << 5) + low;
      const int Rb = Ra + 16;
      float4v s0 = {0.f,0.f,0.f,0.f}, s1 = {0.f,0.f,0.f,0.f};
      for (int kc = 0; kc < 4; ++kc) {
        short8 kf0 = *(const short8*)&Ks[Ra * 128 + (((kc * 4 + quad) + Ra) & 15) * 8];
        short8 kf1 = *(const short8*)&Ks[Rb * 128 + (((kc * 4 + quad) + Rb) & 15) * 8];
        // SWAPPED: S^T = K . Q^T -> lane(low,quad) reg r = P[q0+low][c0 + quad*4 + r]
        s0 = __builtin_amdgcn_mfma_f32_16x16x32_bf16(kf0, qa[kc], s0, 0, 0, 0);
        s1 = __builtin_amdgcn_mfma_f32_16x16x32_bf16(kf1, qa[kc], s1, 0, 0, 0);
      }
      if (c0 + 31 > q0) {
        const int qrow = q0 + low;
        for (int r = 0; r < 4; ++r) {
          s0[r] = (c0 + quad * 4 + r      <= qrow) ? s0[r] : -1e30f;
          s1[r] = (c0 + 16 + quad * 4 + r <= qrow) ? s1[r] : -1e30f;
        }
      }
      // max-free softmax: P = exp2(s); l accumulates lane-locally (q-row = low)
      for (int r = 0; r < 4; ++r) {
        s0[r] = EXP2F(s0[r]);               // masked -1e30 -> 0
        s1[r] = EXP2F(s1[r]);
      }
      l += (s0[0] + s0[1]) + (s0[2] + s0[3]) + (s1[0] + s1[1]) + (s1[2] + s1[3]);

      // P A-fragment, k-permuted: pi(p=8q+j) = 4q+(j&3)+16*(j>=4) — in registers
      uint4v pu = { bfpack2(s0[0], s0[1]), bfpack2(s0[2], s0[3]),
                    bfpack2(s1[0], s1[1]), bfpack2(s1[2], s1[3]) };
      short8 pa = __builtin_bit_cast(short8, pu);

      // V B-fragment: slot sl=4h+quad of the permuted image = one b128 read
      const int sl = (h << 2) + quad;
      for (int nt = 0; nt < 8; ++nt) {
        int d = nt * 16 + low;
        short8 vf = *(const short8*)&Vt[d * 64 + ((sl + d) & 7) * 8];
        accv[nt] = __builtin_amdgcn_mfma_f32_16x16x32_bf16(pa, vf, accv[nt], 0, 0, 0);
      }
    }
  }

  // reduce l across quads (lanes low, low+16, low+32, low+48 share q-row = low)
  l += __shfl_xor(l, 16);
  l += __shfl_xor(l, 32);
  // redistribute to accv row layout: row = quad*4 + r
  float lr[4];
  for (int r = 0; r < 4; ++r) lr[r] = __shfl(l, quad * 4 + r);

  if (g == 1) {
    float inv[4];
    for (int r = 0; r < 4; ++r) inv[r] = 1.f / lr[r];
    float* ob = out + ((size_t)b * SEQ_T + q0) * HDIM;
    for (int nt = 0; nt < 8; ++nt)
      for (int r = 0; r < 4; ++r)
        ob[(size_t)(quad * 4 + r) * HDIM + nt * 16 + low] = accv[nt][r] * inv[r];
  } else {
    const int slot = b * ChunkCfg<CS>::SPB + (cum - ChunkCfg<CS>::QB0) + k;
    unsigned short* op = Opart + (size_t)slot * 16384 + (size_t)qt * 16 * 128;
    for (int nt = 0; nt < 8; ++nt)
      for (int r = 0; r < 4; ++r)
        op[(size_t)(quad * 4 + r) * 128 + nt * 16 + low] = f2bf(accv[nt][r]);
    if (low == 0) {
      float* ml = mlpart + (size_t)slot * 256;
      for (int r = 0; r < 4; ++r)
        ml[qt * 16 + quad * 4 + r] = lr[r];   // shared scale: only l needed
    }
  }
}

// ============================ merge (no max, no exp2) ============================
// Boundary-agnostic: only the chunk COUNT per qb matters (same ceil formula).
template<int CS>
__global__ __launch_bounds__(256) void merge_k(const unsigned short* __restrict__ Opart,
                                               const float* __restrict__ mlpart,
                                               float* __restrict__ out) {
  const int QB0 = ChunkCfg<CS>::QB0;
  const int rowsPB = (16 - QB0) * 128;
  const int ri  = blockIdx.x * 2 + (threadIdx.x >> 7);
  const int b   = ri / rowsPB;
  const int r2  = ri - b * rowsPB;
  const int qb  = QB0 + (r2 >> 7);
  const int row = r2 & 127;
  const int d   = threadIdx.x & 127;
  const int g   = (2 * qb + 2 + CS - 1) / CS;
  int cum = 0;
  for (int i = 0; i < qb; ++i) cum += (2 * i + 2 + CS - 1) / CS;
  const int s0 = b * ChunkCfg<CS>::SPB + cum - QB0;

  float num = 0.f, den = 0.f;
  for (int k = 0; k < g; ++k) {
    den += mlpart[(size_t)(s0 + k) * 256 + row];
    num += bf2f(Opart[(size_t)(s0 + k) * 16384 + (size_t)row * 128 + d]);
  }
  out[((size_t)b * SEQ_T + qb * 128 + row) * HDIM + d] = num / den;
}

// ============================ no-ws fallback (R4, online softmax) ============================
__global__ __launch_bounds__(512, 4) void attn_fb(const float* __restrict__ x,
                                                  float* __restrict__ out) {
  const int b    = blockIdx.y;
  const int qblk = (int)gridDim.x - 1 - (int)blockIdx.x;
  const int qb0  = qblk << 6;
  const int tid  = threadIdx.x;
  const int wave = tid >> 6;
  const int lane = tid & 63;
  const int low  = lane & 15;
  const int quad = lane >> 4;
  const int qt   = wave & 3;
  const int half = wave >> 2;
  const int q0   = qb0 + (qt << 4);
  __shared__ __align__(16) unsigned char smem[48128];
  unsigned short* Ks = (unsigned short*)smem;
  unsigned short* Vt = (unsigned short*)(smem + 17408);
  unsigned short* Ps = (unsigned short*)(smem + 37888);
  float* Om = (float*)smem;
  float* Ml = (float*)(smem + 33792);
  const float* xb = x + (size_t)b * (SEQ_T * 3 * HDIM);
  const float qs = 0.08838834764831845f * 1.4426950408889634f;
  short8 qa[4];
  {
    const float* qrow = xb + (size_t)(q0 + low) * 384 + 128;
    for (int kc = 0; kc < 4; ++kc) {
      float4v f0 = *(const float4v*)(qrow + kc * 32 + quad * 8);
      float4v f1 = *(const float4v*)(qrow + kc * 32 + quad * 8 + 4);
      uint4v u = { bfpack2(f0[0] * qs, f0[1] * qs), bfpack2(f0[2] * qs, f0[3] * qs),
                   bfpack2(f1[0] * qs, f1[1] * qs), bfpack2(f1[2] * qs, f1[3] * qs) };
      qa[kc] = __builtin_bit_cast(short8, u);
    }
  }
  float4v accv[8];
  for (int i = 0; i < 8; ++i) accv[i] = (float4v){0.f, 0.f, 0.f, 0.f};
  float m_i[4] = {-1e30f, -1e30f, -1e30f, -1e30f};
  float l_i[4] = {0.f, 0.f, 0.f, 0.f};
  const int nsuper = qblk + 1;
  for (int s = 0; s < nsuper; ++s) {
    const int r0 = s << 6;
    __syncthreads();
    for (int i = 0; i < 4; ++i) {
      int f = tid + (i << 9);
      int row = f >> 5;
      int c4 = (f & 31) << 2;
      float4v kf = *(const float4v*)(xb + (size_t)(r0 + row) * 384 + c4);
      *(uint2*)&Ks[(row >> 5) * 4352 + (row & 31) * 136 + c4] =
          make_uint2(bfpack2(kf[0], kf[1]), bfpack2(kf[2], kf[3]));
    }
    {
      int kb = tid >> 5, db = tid & 31;
      int til = kb >> 3, kbl = kb & 7;
      const float* vbase = xb + (size_t)(r0 + 4 * kb) * 384 + 256 + 4 * db;
      float4v v0 = *(const float4v*)(vbase);
      float4v v1 = *(const float4v*)(vbase + 384);
      float4v v2 = *(const float4v*)(vbase + 768);
      float4v v3 = *(const float4v*)(vbase + 1152);
      unsigned short* vv = Vt + til * 5120;
      for (int j = 0; j < 4; ++j) {
        int d = 4 * db + j;
        int pb = ((kbl >> 1) + (d >> 3)) & 3;
        *(uint2*)&vv[d * 40 + pb * 8 + (kbl & 1) * 4] =
            make_uint2(bfpack2(v0[j], v1[j]), bfpack2(v2[j], v3[j]));
      }
    }
    __syncthreads();
    const int c0 = r0 + (half << 5);
    if (c0 <= q0 + 15) {
      const unsigned short* Ksp = Ks + half * 4352;
      const unsigned short* Vtp = Vt + half * 5120;
      float4v s0 = {0.f,0.f,0.f,0.f}, s1 = {0.f,0.f,0.f,0.f};
      for (int kc = 0; kc < 4; ++kc) {
        short8 kf0 = *(const short8*)&Ksp[low * 136 + kc * 32 + quad * 8];
        short8 kf1 = *(const short8*)&Ksp[(16 + low) * 136 + kc * 32 + quad * 8];
        s0 = __builtin_amdgcn_mfma_f32_16x16x32_bf16(qa[kc], kf0, s0, 0, 0, 0);
        s1 = __builtin_amdgcn_mfma_f32_16x16x32_bf16(qa[kc], kf1, s1, 0, 0, 0);
      }
      if (c0 + 31 > q0) {
        for (int r = 0; r < 4; ++r) {
          int qrow = q0 + quad * 4 + r;
          s0[r] = (c0 + low      <= qrow) ? s0[r] : -1e30f;
          s1[r] = (c0 + 16 + low <= qrow) ? s1[r] : -1e30f;
        }
      }
      float rmax[4], alpha[4];
      for (int r = 0; r < 4; ++r) rmax[r] = dpp_max16(fmaxf(s0[r], s1[r]));
      for (int r = 0; r < 4; ++r) {
        float mn = fmaxf(m_i[r], rmax[r]);
        alpha[r] = EXP2F(m_i[r] - mn);
        m_i[r] = mn;
      }
      for (int r = 0; r < 4; ++r) {
        s0[r] = EXP2F(s0[r] - m_i[r]);
        s1[r] = EXP2F(s1[r] - m_i[r]);
      }
      float rs[4];
      for (int r = 0; r < 4; ++r) rs[r] = dpp_sum16(s0[r] + s1[r]);
      for (int r = 0; r < 4; ++r) l_i[r] = l_i[r] * alpha[r] + rs[r];
      for (int nt = 0; nt < 8; ++nt)
        for (int r = 0; r < 4; ++r) accv[nt][r] *= alpha[r];
      unsigned short* pw = Ps + wave * 640;
      for (int r = 0; r < 4; ++r) {
        int row = quad * 4 + r;
        pw[row * 40 + low]      = f2bf(s0[r]);
        pw[row * 40 + 16 + low] = f2bf(s1[r]);
      }
      short8 pa = *(const short8*)&pw[low * 40 + quad * 8];
      for (int nt = 0; nt < 8; ++nt) {
        int d = nt * 16 + low;
        int pb = (quad + (d >> 3)) & 3;
        short8 vf = *(const short8*)&Vtp[d * 40 + pb * 8];
        accv[nt] = __builtin_amdgcn_mfma_f32_16x16x32_bf16(pa, vf, accv[nt], 0, 0, 0);
      }
    }
  }
  __syncthreads();
  if (half == 1) {
    float* om = Om + qt * 2112;
    for (int nt = 0; nt < 8; ++nt)
      for (int r = 0; r < 4; ++r)
        om[(quad * 4 + r) * 132 + nt * 16 + low] = accv[nt][r];
    if (low == 0) {
      for (int r = 0; r < 4; ++r) {
        Ml[qt * 32 + quad * 4 + r]      = m_i[r];
        Ml[qt * 32 + 16 + quad * 4 + r] = l_i[r];
      }
    }
  }
  __syncthreads();
  if (half == 0) {
    float aA[4], aB[4], linv[4];
    for (int r = 0; r < 4; ++r) {
      float mB = Ml[qt * 32 + quad * 4 + r];
      float lB = Ml[qt * 32 + 16 + quad * 4 + r];
      float mN = fmaxf(m_i[r], mB);
      aA[r] = EXP2F(m_i[r] - mN);
      aB[r] = EXP2F(mB - mN);
      linv[r] = 1.f / (l_i[r] * aA[r] + lB * aB[r]);
    }
    const float* om = Om + qt * 2112;
    float* ob = out + ((size_t)b * SEQ_T + q0) * HDIM;
    for (int nt = 0; nt < 8; ++nt)
      for (int r = 0; r < 4; ++r) {
        float o = accv[nt][r] * aA[r] + om[(quad * 4 + r) * 132 + nt * 16 + low] * aB[r];
        ob[(size_t)(quad * 4 + r) * HDIM + nt * 16 + low] = o * linv[r];
      }
  }
}

extern "C" void kernel_launch(void* const* d_in, const int* in_sizes, int n_in,
                              void* d_out, int out_size, void* d_ws, size_t ws_size,
                              hipStream_t stream) {
  const float* x = (const float*)d_in[0];
  float* out = (float*)d_out;
  const size_t PRE = (size_t)NB * NTILES * TILE_SHORTS * 2 * sizeof(unsigned short); // 16 MB

  // thresholds unchanged (CS=5 needs 59 slots < the 70-slot CS=4 allocation)
  const size_t OP4 = (size_t)NB * 70 * 16384 * sizeof(unsigned short);   // 36.7 MB
  const size_t ML4 = (size_t)NB * 70 * 256 * sizeof(float);
  const size_t OP8 = (size_t)NB * 36 * 16384 * sizeof(unsigned short);   // 18.9 MB
  const size_t ML8 = (size_t)NB * 36 * 256 * sizeof(float);

  unsigned short* kbuf = (unsigned short*)d_ws;
  unsigned short* vbuf = kbuf + (size_t)NB * NTILES * TILE_SHORTS;

  if (ws_size >= PRE + OP4 + ML4) {
    unsigned short* Opart = (unsigned short*)((char*)d_ws + PRE);
    float*          mlp   = (float*)((char*)d_ws + PRE + OP4);
    hipLaunchKernelGGL(prepass2, dim3(NB * NTILES * 2), dim3(256), 0, stream, x, kbuf, vbuf);
    hipLaunchKernelGGL((attn_chunk_k<5>), dim3(NB * 61), dim3(512), 0, stream,
                       x, kbuf, vbuf, Opart, mlp, out);
    hipLaunchKernelGGL((merge_k<5>), dim3(NB * 14 * 128 / 2), dim3(256), 0, stream,
                       Opart, mlp, out);
  } else if (ws_size >= PRE + OP8 + ML8) {
    unsigned short* Opart = (unsigned short*)((char*)d_ws + PRE);
    float*          mlp   = (float*)((char*)d_ws + PRE + OP8);
    hipLaunchKernelGGL(prepass2, dim3(NB * NTILES * 2), dim3(256), 0, stream, x, kbuf, vbuf);
    hipLaunchKernelGGL((attn_chunk_k<8>), dim3(NB * 40), dim3(512), 0, stream,
                       x, kbuf, vbuf, Opart, mlp, out);
    hipLaunchKernelGGL((merge_k<8>), dim3(NB * 12 * 128 / 2), dim3(256), 0, stream,
                       Opart, mlp, out);
  } else {
    hipLaunchKernelGGL(attn_fb, dim3(SEQ_T / 64, NB), dim3(512), 0, stream, x, out);
  }
}

// Round 12
// 127.499 us; speedup vs baseline: 1.1287x; 1.0682x over previous
//
#include <hip/hip_runtime.h>

#define SEQ_T 2048
#define HDIM  128
#define NB    16
#define NTILES (SEQ_T / 64)          // 32 kv-tiles of 64
#define TILE_SHORTS 8192             // 16 KB per tile (64x128 bf16)

typedef __attribute__((ext_vector_type(8))) short short8;      // 8 bf16 (4 VGPRs)
typedef __attribute__((ext_vector_type(4))) short short4v;     // 4 bf16 (8B)
typedef __attribute__((ext_vector_type(4))) float float4v;
typedef __attribute__((ext_vector_type(4))) unsigned int uint4v;

#define EXP2F(x) __builtin_amdgcn_exp2f(x)

__device__ __forceinline__ unsigned int bfpack2(float a, float b) {
  unsigned int ua = __builtin_bit_cast(unsigned int, a);
  unsigned int ub = __builtin_bit_cast(unsigned int, b);
  return ((ua + 0x8000u) >> 16) | ((ub + 0x8000u) & 0xFFFF0000u);
}
__device__ __forceinline__ unsigned short f2bf(float a) {
  return (unsigned short)((__builtin_bit_cast(unsigned int, a) + 0x8000u) >> 16);
}
__device__ __forceinline__ float bf2f(unsigned short h) {
  unsigned int u = ((unsigned int)h) << 16;
  return __builtin_bit_cast(float, u);
}

__device__ __forceinline__ float dpp_max16(float x) {
  int t;
  t = __builtin_amdgcn_mov_dpp(__builtin_bit_cast(int, x), 0xB1, 0xF, 0xF, true);
  x = fmaxf(x, __builtin_bit_cast(float, t));
  t = __builtin_amdgcn_mov_dpp(__builtin_bit_cast(int, x), 0x4E, 0xF, 0xF, true);
  x = fmaxf(x, __builtin_bit_cast(float, t));
  t = __builtin_amdgcn_mov_dpp(__builtin_bit_cast(int, x), 0x141, 0xF, 0xF, true);
  x = fmaxf(x, __builtin_bit_cast(float, t));
  t = __builtin_amdgcn_mov_dpp(__builtin_bit_cast(int, x), 0x140, 0xF, 0xF, true);
  x = fmaxf(x, __builtin_bit_cast(float, t));
  return x;
}
__device__ __forceinline__ float dpp_sum16(float x) {
  int t;
  t = __builtin_amdgcn_mov_dpp(__builtin_bit_cast(int, x), 0xB1, 0xF, 0xF, true);
  x += __builtin_bit_cast(float, t);
  t = __builtin_amdgcn_mov_dpp(__builtin_bit_cast(int, x), 0x4E, 0xF, 0xF, true);
  x += __builtin_bit_cast(float, t);
  t = __builtin_amdgcn_mov_dpp(__builtin_bit_cast(int, x), 0x141, 0xF, 0xF, true);
  x += __builtin_bit_cast(float, t);
  t = __builtin_amdgcn_mov_dpp(__builtin_bit_cast(int, x), 0x140, 0xF, 0xF, true);
  x += __builtin_bit_cast(float, t);
  return x;
}

// chunks per batch / partial slots per batch for chunk size CS (super-iters).
// CS=5 balanced chunking -> CPB=61 -> 976 blocks <= 1024 co-resident slots:
// whole grid runs in ONE scheduling round (R10 win).
template<int CS> struct ChunkCfg;
template<> struct ChunkCfg<5> { static const int CPB = 61, SPB = 59, QB0 = 2; };
template<> struct ChunkCfg<8> { static const int CPB = 40, SPB = 36, QB0 = 4; };

// ============================ prepass (R9: half-tile split) ============================
// Bit-identical kbuf/vbuf images to the R5 prepass. One block per (b, tile, half).
__global__ __launch_bounds__(256) void prepass2(const float* __restrict__ x,
                                                unsigned short* __restrict__ kbuf,
                                                unsigned short* __restrict__ vbuf) {
  const int bid = blockIdx.x;
  const int b   = bid >> 6;            // 64 half-tiles per batch
  const int rem = bid & 63;
  const int t   = rem >> 1;            // 64-kv tile
  const int h   = rem & 1;             // half
  const int tid = threadIdx.x;
  __shared__ __align__(16) unsigned short Klds[4096];  // [32 rows][128 cols]
  __shared__ __align__(16) unsigned short Vlds[4096];  // local d in [0,64): [d][slot][8]

  const float* xb = x + (size_t)b * (SEQ_T * 384) + (size_t)t * 64 * 384;

  // K: rows 32h..32h+31, cols 0..127
  for (int i = 0; i < 4; ++i) {
    int idx = tid + i * 256;                    // 0..1023
    int rl = idx >> 5, c4 = (idx & 31) << 2;
    float4v f = *(const float4v*)(xb + (size_t)(32 * h + rl) * 384 + c4);
    *(uint2*)&Klds[rl * 128 + c4] = make_uint2(bfpack2(f[0], f[1]), bfpack2(f[2], f[3]));
  }
  // V: all 64 rows, cols 64h..64h+63
  {
    int kb = tid >> 4, db2 = tid & 15;          // kb: 16 groups of 4 rows
    int c4 = 64 * h + 4 * db2;
    const float* vb = xb + (size_t)(4 * kb) * 384 + 256 + c4;
    float4v v0 = *(const float4v*)(vb);
    float4v v1 = *(const float4v*)(vb + 384);
    float4v v2 = *(const float4v*)(vb + 768);
    float4v v3 = *(const float4v*)(vb + 1152);
    int sl = ((kb >> 3) << 2) | (kb & 3);       // permuted slot (R5 mapping)
    int o  = ((kb >> 2) & 1) * 4;
    for (int j = 0; j < 4; ++j) {
      int d = c4 + j;
      *(uint2*)&Vlds[(d - 64 * h) * 64 + ((sl + d) & 7) * 8 + o] =
          make_uint2(bfpack2(v0[j], v1[j]), bfpack2(v2[j], v3[j]));
    }
  }
  __syncthreads();

  unsigned short* kdst = kbuf + (size_t)(b * NTILES + t) * TILE_SHORTS;
  unsigned short* vdst = vbuf + (size_t)(b * NTILES + t) * TILE_SHORTS;
  for (int i = 0; i < 2; ++i) {
    int nloc = tid + i * 256;                   // 0..511
    int n = 512 * h + nloc;                     // global unit
    int rl = nloc >> 4, pu = nloc & 15;
    int u = (pu - (32 * h + rl)) & 15;          // == (pu - rl) & 15 since 32h%16==0
    *(uint4v*)&kdst[n * 8] = *(const uint4v*)&Klds[rl * 128 + u * 8];
    *(uint4v*)&vdst[n * 8] = *(const uint4v*)&Vlds[nloc * 8];  // final image
  }
}

// ============================ chunked attention ============================
// R5 PROVEN COMPUTE BODY + R10 CS=5 single-round packing + R11 T1 XCD placement
// (XCD x serves batches {x, x+8}: K/V L2-resident, FETCH 71->17MB — verified).
// LEDGER:
//  * single-barrier global_load_lds DMA: corrupted TWICE — banned.
//  * R4 V b64 pair-read: 4-way bank conflict — retired.
//  * R6 256-row/2-blocks-per-CU: +24% — inter-block TLP (4 blocks/CU) is the
//    dominant latency-hiding resource; never trade it away.
//  * R7 T5 setprio around MFMA clusters: −12% (starves staging waves) — retired.
//  * R8 KVBLK=32 V half-image: conflicts 2.13M->4.26M — retired.
//  * R11 falsification: with K/V L2-resident (FETCH 17MB) attn time is FLAT ->
//    the kernel is intra-block-schedule-bound at ~42us, NOT memory-bound. The
//    only untried lever is the full 8-phase counted-vmcnt rewrite (high risk).
//  * Fixed costs (R10/R11 counters): 2x 256MiB harness poison fills at 80% of
//    HBM peak ≈ 84us/iteration — their own roofline, untouchable.
// launch_bounds(512,4): (512,8) collapses the allocator (prior session R7).
template<int CS>
__global__ __launch_bounds__(512, 4) void attn_chunk_k(const float* __restrict__ x,
                                                       const unsigned short* __restrict__ kbuf,
                                                       const unsigned short* __restrict__ vbuf,
                                                       unsigned short* __restrict__ Opart,
                                                       float* __restrict__ mlpart,
                                                       float* __restrict__ out) {
  const int f = blockIdx.x;
  // T1: XCD x (= f & 7, HW round-robin) serves batches {x, x+8}
  const int x7   = f & 7;
  const int j    = f >> 3;                       // 0 .. 2*CPB-1
  const int hi   = (j >= ChunkCfg<CS>::CPB) ? 1 : 0;
  const int b    = x7 + 8 * hi;
  int c = j - hi * ChunkCfg<CS>::CPB;
  c = ChunkCfg<CS>::CPB - 1 - c;                 // LPT: longest chunks first
  int qb = 0, cum = 0;
  for (;;) {
    int gg = (2 * qb + 2 + CS - 1) / CS;
    if (c < cum + gg) break;
    cum += gg; ++qb;
  }
  const int n = 2 * qb + 2;
  const int g = (n + CS - 1) / CS;
  const int k = c - cum;
  const int sBeg = (k * n) / g;            // balanced split (sizes 2..CS)
  const int sEnd = ((k + 1) * n) / g;

  const int tid  = threadIdx.x;
  const int qt   = tid >> 6;
  const int lane = tid & 63;
  const int low  = lane & 15;
  const int quad = lane >> 4;
  const int q0   = qb * 128 + qt * 16;

  __shared__ __align__(16) unsigned char smem[32768];    // K tile + V tile only
  unsigned short* Ks = (unsigned short*)smem;            // 16 KB swizzled K tile
  unsigned short* Vt = (unsigned short*)(smem + 16384);  // 16 KB swizzled V^T tile

  const float* xb = x + (size_t)b * (SEQ_T * 3 * HDIM);
  const unsigned short* kt = kbuf + (size_t)b * NTILES * TILE_SHORTS;
  const unsigned short* vt = vbuf + (size_t)b * NTILES * TILE_SHORTS;

  const float qs = 0.08838834764831845f * 1.4426950408889634f;
  short8 qa[4];
  {
    const float* qrow = xb + (size_t)(q0 + low) * 384 + 128;
    for (int kc = 0; kc < 4; ++kc) {
      float4v f0 = *(const float4v*)(qrow + kc * 32 + quad * 8);
      float4v f1 = *(const float4v*)(qrow + kc * 32 + quad * 8 + 4);
      uint4v u = { bfpack2(f0[0] * qs, f0[1] * qs), bfpack2(f0[2] * qs, f0[3] * qs),
                   bfpack2(f1[0] * qs, f1[1] * qs), bfpack2(f1[2] * qs, f1[3] * qs) };
      qa[kc] = __builtin_bit_cast(short8, u);
    }
  }

  float4v accv[8];
  for (int i = 0; i < 8; ++i) accv[i] = (float4v){0.f, 0.f, 0.f, 0.f};
  float l = 0.f;                         // per-lane: q-row = low

  const int ch = qt * 2;

  // T14 staging registers: this wave's 2 K-chunks + 2 V-chunks, 16B/lane each
  uint4v kr0, kr1, vr0, vr1;
  {
    const unsigned short* ksrc = kt + (size_t)sBeg * TILE_SHORTS;
    const unsigned short* vsrc = vt + (size_t)sBeg * TILE_SHORTS;
    kr0 = *(const uint4v*)(ksrc + (size_t)ch * 512 + lane * 8);
    kr1 = *(const uint4v*)(ksrc + (size_t)(ch + 1) * 512 + lane * 8);
    vr0 = *(const uint4v*)(vsrc + (size_t)ch * 512 + lane * 8);
    vr1 = *(const uint4v*)(vsrc + (size_t)(ch + 1) * 512 + lane * 8);
  }

  for (int s = sBeg; s < sEnd; ++s) {
    __syncthreads();   // all waves done reading previous tile; prev prefetch drained

    *(uint4v*)&Ks[(size_t)ch * 512 + lane * 8]       = kr0;
    *(uint4v*)&Ks[(size_t)(ch + 1) * 512 + lane * 8] = kr1;
    *(uint4v*)&Vt[(size_t)ch * 512 + lane * 8]       = vr0;
    *(uint4v*)&Vt[(size_t)(ch + 1) * 512 + lane * 8] = vr1;

    __syncthreads();   // tile-s image visible to all waves

    if (s + 1 < sEnd) {   // prefetch next tile; latency hides under compute below
      const unsigned short* ksrc = kt + (size_t)(s + 1) * TILE_SHORTS;
      const unsigned short* vsrc = vt + (size_t)(s + 1) * TILE_SHORTS;
      kr0 = *(const uint4v*)(ksrc + (size_t)ch * 512 + lane * 8);
      kr1 = *(const uint4v*)(ksrc + (size_t)(ch + 1) * 512 + lane * 8);
      vr0 = *(const uint4v*)(vsrc + (size_t)ch * 512 + lane * 8);
      vr1 = *(const uint4v*)(vsrc + (size_t)(ch + 1) * 512 + lane * 8);
    }

    for (int h = 0; h < 2; ++h) {
      const int c0 = s * 64 + h * 32;
      if (c0 > q0 + 15) continue;
      const int Ra = (h << 5) + low;
      const int Rb = Ra + 16;
      float4v s0 = {0.f,0.f,0.f,0.f}, s1 = {0.f,0.f,0.f,0.f};
      for (int kc = 0; kc < 4; ++kc) {
        short8 kf0 = *(const short8*)&Ks[Ra * 128 + (((kc * 4 + quad) + Ra) & 15) * 8];
        short8 kf1 = *(const short8*)&Ks[Rb * 128 + (((kc * 4 + quad) + Rb) & 15) * 8];
        // SWAPPED: S^T = K . Q^T -> lane(low,quad) reg r = P[q0+low][c0 + quad*4 + r]
        s0 = __builtin_amdgcn_mfma_f32_16x16x32_bf16(kf0, qa[kc], s0, 0, 0, 0);
        s1 = __builtin_amdgcn_mfma_f32_16x16x32_bf16(kf1, qa[kc], s1, 0, 0, 0);
      }
      if (c0 + 31 > q0) {
        const int qrow = q0 + low;
        for (int r = 0; r < 4; ++r) {
          s0[r] = (c0 + quad * 4 + r      <= qrow) ? s0[r] : -1e30f;
          s1[r] = (c0 + 16 + quad * 4 + r <= qrow) ? s1[r] : -1e30f;
        }
      }
      // max-free softmax: P = exp2(s); l accumulates lane-locally (q-row = low)
      for (int r = 0; r < 4; ++r) {
        s0[r] = EXP2F(s0[r]);               // masked -1e30 -> 0
        s1[r] = EXP2F(s1[r]);
      }
      l += (s0[0] + s0[1]) + (s0[2] + s0[3]) + (s1[0] + s1[1]) + (s1[2] + s1[3]);

      // P A-fragment, k-permuted: pi(p=8q+j) = 4q+(j&3)+16*(j>=4) — in registers
      uint4v pu = { bfpack2(s0[0], s0[1]), bfpack2(s0[2], s0[3]),
                    bfpack2(s1[0], s1[1]), bfpack2(s1[2], s1[3]) };
      short8 pa = __builtin_bit_cast(short8, pu);

      // V B-fragment: slot sl=4h+quad of the permuted image = one b128 read
      const int sl = (h << 2) + quad;
      for (int nt = 0; nt < 8; ++nt) {
        int d = nt * 16 + low;
        short8 vf = *(const short8*)&Vt[d * 64 + ((sl + d) & 7) * 8];
        accv[nt] = __builtin_amdgcn_mfma_f32_16x16x32_bf16(pa, vf, accv[nt], 0, 0, 0);
      }
    }
  }

  // reduce l across quads (lanes low, low+16, low+32, low+48 share q-row = low)
  l += __shfl_xor(l, 16);
  l += __shfl_xor(l, 32);
  // redistribute to accv row layout: row = quad*4 + r
  float lr[4];
  for (int r = 0; r < 4; ++r) lr[r] = __shfl(l, quad * 4 + r);

  if (g == 1) {
    float inv[4];
    for (int r = 0; r < 4; ++r) inv[r] = 1.f / lr[r];
    float* ob = out + ((size_t)b * SEQ_T + q0) * HDIM;
    for (int nt = 0; nt < 8; ++nt)
      for (int r = 0; r < 4; ++r)
        ob[(size_t)(quad * 4 + r) * HDIM + nt * 16 + low] = accv[nt][r] * inv[r];
  } else {
    const int slot = b * ChunkCfg<CS>::SPB + (cum - ChunkCfg<CS>::QB0) + k;
    unsigned short* op = Opart + (size_t)slot * 16384 + (size_t)qt * 16 * 128;
    for (int nt = 0; nt < 8; ++nt)
      for (int r = 0; r < 4; ++r)
        op[(size_t)(quad * 4 + r) * 128 + nt * 16 + low] = f2bf(accv[nt][r]);
    if (low == 0) {
      float* ml = mlpart + (size_t)slot * 256;
      for (int r = 0; r < 4; ++r)
        ml[qt * 16 + quad * 4 + r] = lr[r];   // shared scale: only l needed
    }
  }
}

// ============================ merge (R12: G13-vectorized) ============================
// Each thread owns 4 consecutive d's: short4 (8B) Opart loads + float4 (16B)
// out store, vs the old scalar ushort (2B) / float (4B). Same k-ascending sum
// order per element -> bit-identical output. 256 thr = 8 rows/block.
template<int CS>
__global__ __launch_bounds__(256) void merge_k(const unsigned short* __restrict__ Opart,
                                               const float* __restrict__ mlpart,
                                               float* __restrict__ out) {
  const int QB0 = ChunkCfg<CS>::QB0;
  const int rowsPB = (16 - QB0) * 128;
  const int gri = blockIdx.x * 8 + (threadIdx.x >> 5);   // global row index
  const int b   = gri / rowsPB;
  const int r2  = gri - b * rowsPB;
  const int qb  = QB0 + (r2 >> 7);
  const int row = r2 & 127;
  const int dq  = (threadIdx.x & 31) << 2;               // d quad base
  const int g   = (2 * qb + 2 + CS - 1) / CS;
  int cum = 0;
  for (int i = 0; i < qb; ++i) cum += (2 * i + 2 + CS - 1) / CS;
  const int s0 = b * ChunkCfg<CS>::SPB + cum - QB0;

  float num0 = 0.f, num1 = 0.f, num2 = 0.f, num3 = 0.f, den = 0.f;
  for (int k = 0; k < g; ++k) {
    den += mlpart[(size_t)(s0 + k) * 256 + row];
    short4v v = *(const short4v*)&Opart[(size_t)(s0 + k) * 16384 + (size_t)row * 128 + dq];
    num0 += bf2f((unsigned short)v[0]);
    num1 += bf2f((unsigned short)v[1]);
    num2 += bf2f((unsigned short)v[2]);
    num3 += bf2f((unsigned short)v[3]);
  }
  float inv = 1.f / den;
  float4v o = { num0 * inv, num1 * inv, num2 * inv, num3 * inv };
  *(float4v*)&out[((size_t)b * SEQ_T + qb * 128 + row) * HDIM + dq] = o;
}

// ============================ no-ws fallback (R4, online softmax) ============================
__global__ __launch_bounds__(512, 4) void attn_fb(const float* __restrict__ x,
                                                  float* __restrict__ out) {
  const int b    = blockIdx.y;
  const int qblk = (int)gridDim.x - 1 - (int)blockIdx.x;
  const int qb0  = qblk << 6;
  const int tid  = threadIdx.x;
  const int wave = tid >> 6;
  const int lane = tid & 63;
  const int low  = lane & 15;
  const int quad = lane >> 4;
  const int qt   = wave & 3;
  const int half = wave >> 2;
  const int q0   = qb0 + (qt << 4);
  __shared__ __align__(16) unsigned char smem[48128];
  unsigned short* Ks = (unsigned short*)smem;
  unsigned short* Vt = (unsigned short*)(smem + 17408);
  unsigned short* Ps = (unsigned short*)(smem + 37888);
  float* Om = (float*)smem;
  float* Ml = (float*)(smem + 33792);
  const float* xb = x + (size_t)b * (SEQ_T * 3 * HDIM);
  const float qs = 0.08838834764831845f * 1.4426950408889634f;
  short8 qa[4];
  {
    const float* qrow = xb + (size_t)(q0 + low) * 384 + 128;
    for (int kc = 0; kc < 4; ++kc) {
      float4v f0 = *(const float4v*)(qrow + kc * 32 + quad * 8);
      float4v f1 = *(const float4v*)(qrow + kc * 32 + quad * 8 + 4);
      uint4v u = { bfpack2(f0[0] * qs, f0[1] * qs), bfpack2(f0[2] * qs, f0[3] * qs),
                   bfpack2(f1[0] * qs, f1[1] * qs), bfpack2(f1[2] * qs, f1[3] * qs) };
      qa[kc] = __builtin_bit_cast(short8, u);
    }
  }
  float4v accv[8];
  for (int i = 0; i < 8; ++i) accv[i] = (float4v){0.f, 0.f, 0.f, 0.f};
  float m_i[4] = {-1e30f, -1e30f, -1e30f, -1e30f};
  float l_i[4] = {0.f, 0.f, 0.f, 0.f};
  const int nsuper = qblk + 1;
  for (int s = 0; s < nsuper; ++s) {
    const int r0 = s << 6;
    __syncthreads();
    for (int i = 0; i < 4; ++i) {
      int f = tid + (i << 9);
      int row = f >> 5;
      int c4 = (f & 31) << 2;
      float4v kf = *(const float4v*)(xb + (size_t)(r0 + row) * 384 + c4);
      *(uint2*)&Ks[(row >> 5) * 4352 + (row & 31) * 136 + c4] =
          make_uint2(bfpack2(kf[0], kf[1]), bfpack2(kf[2], kf[3]));
    }
    {
      int kb = tid >> 5, db = tid & 31;
      int til = kb >> 3, kbl = kb & 7;
      const float* vbase = xb + (size_t)(r0 + 4 * kb) * 384 + 256 + 4 * db;
      float4v v0 = *(const float4v*)(vbase);
      float4v v1 = *(const float4v*)(vbase + 384);
      float4v v2 = *(const float4v*)(vbase + 768);
      float4v v3 = *(const float4v*)(vbase + 1152);
      unsigned short* vv = Vt + til * 5120;
      for (int j = 0; j < 4; ++j) {
        int d = 4 * db + j;
        int pb = ((kbl >> 1) + (d >> 3)) & 3;
        *(uint2*)&vv[d * 40 + pb * 8 + (kbl & 1) * 4] =
            make_uint2(bfpack2(v0[j], v1[j]), bfpack2(v2[j], v3[j]));
      }
    }
    __syncthreads();
    const int c0 = r0 + (half << 5);
    if (c0 <= q0 + 15) {
      const unsigned short* Ksp = Ks + half * 4352;
      const unsigned short* Vtp = Vt + half * 5120;
      float4v s0 = {0.f,0.f,0.f,0.f}, s1 = {0.f,0.f,0.f,0.f};
      for (int kc = 0; kc < 4; ++kc) {
        short8 kf0 = *(const short8*)&Ksp[low * 136 + kc * 32 + quad * 8];
        short8 kf1 = *(const short8*)&Ksp[(16 + low) * 136 + kc * 32 + quad * 8];
        s0 = __builtin_amdgcn_mfma_f32_16x16x32_bf16(qa[kc], kf0, s0, 0, 0, 0);
        s1 = __builtin_amdgcn_mfma_f32_16x16x32_bf16(qa[kc], kf1, s1, 0, 0, 0);
      }
      if (c0 + 31 > q0) {
        for (int r = 0; r < 4; ++r) {
          int qrow = q0 + quad * 4 + r;
          s0[r] = (c0 + low      <= qrow) ? s0[r] : -1e30f;
          s1[r] = (c0 + 16 + low <= qrow) ? s1[r] : -1e30f;
        }
      }
      float rmax[4], alpha[4];
      for (int r = 0; r < 4; ++r) rmax[r] = dpp_max16(fmaxf(s0[r], s1[r]));
      for (int r = 0; r < 4; ++r) {
        float mn = fmaxf(m_i[r], rmax[r]);
        alpha[r] = EXP2F(m_i[r] - mn);
        m_i[r] = mn;
      }
      for (int r = 0; r < 4; ++r) {
        s0[r] = EXP2F(s0[r] - m_i[r]);
        s1[r] = EXP2F(s1[r] - m_i[r]);
      }
      float rs[4];
      for (int r = 0; r < 4; ++r) rs[r] = dpp_sum16(s0[r] + s1[r]);
      for (int r = 0; r < 4; ++r) l_i[r] = l_i[r] * alpha[r] + rs[r];
      for (int nt = 0; nt < 8; ++nt)
        for (int r = 0; r < 4; ++r) accv[nt][r] *= alpha[r];
      unsigned short* pw = Ps + wave * 640;
      for (int r = 0; r < 4; ++r) {
        int row = quad * 4 + r;
        pw[row * 40 + low]      = f2bf(s0[r]);
        pw[row * 40 + 16 + low] = f2bf(s1[r]);
      }
      short8 pa = *(const short8*)&pw[low * 40 + quad * 8];
      for (int nt = 0; nt < 8; ++nt) {
        int d = nt * 16 + low;
        int pb = (quad + (d >> 3)) & 3;
        short8 vf = *(const short8*)&Vtp[d * 40 + pb * 8];
        accv[nt] = __builtin_amdgcn_mfma_f32_16x16x32_bf16(pa, vf, accv[nt], 0, 0, 0);
      }
    }
  }
  __syncthreads();
  if (half == 1) {
    float* om = Om + qt * 2112;
    for (int nt = 0; nt < 8; ++nt)
      for (int r = 0; r < 4; ++r)
        om[(quad * 4 + r) * 132 + nt * 16 + low] = accv[nt][r];
    if (low == 0) {
      for (int r = 0; r < 4; ++r) {
        Ml[qt * 32 + quad * 4 + r]      = m_i[r];
        Ml[qt * 32 + 16 + quad * 4 + r] = l_i[r];
      }
    }
  }
  __syncthreads();
  if (half == 0) {
    float aA[4], aB[4], linv[4];
    for (int r = 0; r < 4; ++r) {
      float mB = Ml[qt * 32 + quad * 4 + r];
      float lB = Ml[qt * 32 + 16 + quad * 4 + r];
      float mN = fmaxf(m_i[r], mB);
      aA[r] = EXP2F(m_i[r] - mN);
      aB[r] = EXP2F(mB - mN);
      linv[r] = 1.f / (l_i[r] * aA[r] + lB * aB[r]);
    }
    const float* om = Om + qt * 2112;
    float* ob = out + ((size_t)b * SEQ_T + q0) * HDIM;
    for (int nt = 0; nt < 8; ++nt)
      for (int r = 0; r < 4; ++r) {
        float o = accv[nt][r] * aA[r] + om[(quad * 4 + r) * 132 + nt * 16 + low] * aB[r];
        ob[(size_t)(quad * 4 + r) * HDIM + nt * 16 + low] = o * linv[r];
      }
  }
}

extern "C" void kernel_launch(void* const* d_in, const int* in_sizes, int n_in,
                              void* d_out, int out_size, void* d_ws, size_t ws_size,
                              hipStream_t stream) {
  const float* x = (const float*)d_in[0];
  float* out = (float*)d_out;
  const size_t PRE = (size_t)NB * NTILES * TILE_SHORTS * 2 * sizeof(unsigned short); // 16 MB

  // thresholds unchanged (CS=5 needs 59 slots < the 70-slot CS=4 allocation)
  const size_t OP4 = (size_t)NB * 70 * 16384 * sizeof(unsigned short);   // 36.7 MB
  const size_t ML4 = (size_t)NB * 70 * 256 * sizeof(float);
  const size_t OP8 = (size_t)NB * 36 * 16384 * sizeof(unsigned short);   // 18.9 MB
  const size_t ML8 = (size_t)NB * 36 * 256 * sizeof(float);

  unsigned short* kbuf = (unsigned short*)d_ws;
  unsigned short* vbuf = kbuf + (size_t)NB * NTILES * TILE_SHORTS;

  if (ws_size >= PRE + OP4 + ML4) {
    unsigned short* Opart = (unsigned short*)((char*)d_ws + PRE);
    float*          mlp   = (float*)((char*)d_ws + PRE + OP4);
    hipLaunchKernelGGL(prepass2, dim3(NB * NTILES * 2), dim3(256), 0, stream, x, kbuf, vbuf);
    hipLaunchKernelGGL((attn_chunk_k<5>), dim3(NB * 61), dim3(512), 0, stream,
                       x, kbuf, vbuf, Opart, mlp, out);
    hipLaunchKernelGGL((merge_k<5>), dim3(NB * 14 * 128 / 8), dim3(256), 0, stream,
                       Opart, mlp, out);
  } else if (ws_size >= PRE + OP8 + ML8) {
    unsigned short* Opart = (unsigned short*)((char*)d_ws + PRE);
    float*          mlp   = (float*)((char*)d_ws + PRE + OP8);
    hipLaunchKernelGGL(prepass2, dim3(NB * NTILES * 2), dim3(256), 0, stream, x, kbuf, vbuf);
    hipLaunchKernelGGL((attn_chunk_k<8>), dim3(NB * 40), dim3(512), 0, stream,
                       x, kbuf, vbuf, Opart, mlp, out);
    hipLaunchKernelGGL((merge_k<8>), dim3(NB * 12 * 128 / 8), dim3(256), 0, stream,
                       Opart, mlp, out);
  } else {
    hipLaunchKernelGGL(attn_fb, dim3(SEQ_T / 64, NB), dim3(512), 0, stream, x, out);
  }
}